// Round 2
// baseline (744.632 us; speedup 1.0000x reference)
//
#include <hip/hip_runtime.h>
#include <hip/hip_bf16.h>

using bf16 = __hip_bfloat16;
typedef __bf16 bf16x8 __attribute__((ext_vector_type(8)));
typedef float f32x4 __attribute__((ext_vector_type(4)));
typedef _Float16 h8 __attribute__((ext_vector_type(8)));
typedef _Float16 h4 __attribute__((ext_vector_type(4)));

#define AS1(p) ((const __attribute__((address_space(1))) void*)(p))
#define AS3(p) ((__attribute__((address_space(3))) void*)(p))

// ---------------------------------------------------------------------------
// Weights: Wt[tap = p*3+q][oc][ic] bf16 (no FIR folding -- FIR is pass B now)
// ---------------------------------------------------------------------------
__global__ void prep_wt_k(const float* __restrict__ w, bf16* __restrict__ wt) {
  const int o = blockIdx.x, i = threadIdx.x;
  const float* wp = w + (size_t)(o * 256 + i) * 9;
#pragma unroll
  for (int p = 0; p < 9; ++p)
    wt[(size_t)p * 65536 + o * 256 + i] = __float2bfloat16(wp[p]);
}

// ---------------------------------------------------------------------------
// x NCHW fp32 -> padded NHWC bf16 [c][66][66][256] (border zero via memset)
// ---------------------------------------------------------------------------
__global__ void xpose_k(const float* __restrict__ x, bf16* __restrict__ xpad) {
  const int b = blockIdx.x;
  const int icb = b & 3, iy = (b >> 2) & 63, n = b >> 8;
  __shared__ bf16 lds[64][72];
  const int t = threadIdx.x;
  const int c = t & 63, ixg = t >> 6;
  const float* src = x + (((size_t)(n * 256 + icb * 64 + c) * 64 + iy) * 64);
#pragma unroll
  for (int rep = 0; rep < 4; ++rep) {
    const int ix0 = ixg * 16 + rep * 4;
    float4 v = *reinterpret_cast<const float4*>(src + ix0);
    lds[ix0 + 0][c] = __float2bfloat16(v.x);
    lds[ix0 + 1][c] = __float2bfloat16(v.y);
    lds[ix0 + 2][c] = __float2bfloat16(v.z);
    lds[ix0 + 3][c] = __float2bfloat16(v.w);
  }
  __syncthreads();
  const int ix = t >> 2, cseg = (t & 3) * 16;
  bf16* dst = xpad + (((size_t)(n * 66 + iy + 1) * 66 + ix + 1) * 256 + icb * 64 + cseg);
  typedef short short8 __attribute__((ext_vector_type(8)));
  *reinterpret_cast<short8*>(dst) = *reinterpret_cast<const short8*>(&lds[ix][cseg]);
  *reinterpret_cast<short8*>(dst + 8) = *reinterpret_cast<const short8*>(&lds[ix][cseg + 8]);
}

// ---------------------------------------------------------------------------
// Zero the pad ring of each y plane-slot [66][66][256] fp16 (once)
// ---------------------------------------------------------------------------
__global__ void zpad_k(_Float16* __restrict__ yy) {
  const size_t PL = (size_t)66 * 66 * 256;
  _Float16* pl = yy + (size_t)blockIdx.x * PL;
  const int t = threadIdx.x;
  for (int idx = t; idx < 66 * 256; idx += 256) {
    pl[idx] = (_Float16)0.f;
    pl[(size_t)65 * 66 * 256 + idx] = (_Float16)0.f;
  }
  for (int idx = t; idx < 64 * 256; idx += 256) {
    const int a = 1 + (idx >> 8), cdx = idx & 255;
    pl[((size_t)a * 66 + 0) * 256 + cdx] = (_Float16)0.f;
    pl[((size_t)a * 66 + 65) * 256 + cdx] = (_Float16)0.f;
  }
}

// ---------------------------------------------------------------------------
// Pass A: 4 y-phase GEMMs. Plane(sy,sx): 0=ee,1=eo,2=oe,3=oo.
//   ee[a,b]=sum_{dp,dq} x[a-1+dp,b-1+dq] w[2dp,2dq]   a,b in 0..64
//   eo[a,b]=sum_{dp}    x[a-1+dp,b     ] w[2dp,1  ]   a 0..64, b 0..63
//   oe[a,b]=sum_{dq}    x[a,     b-1+dq] w[1,  2dq]   a 0..63, b 0..64
//   oo[a,b]=            x[a,     b     ] w[1,  1  ]   a,b 0..63
// Stored y[plane][n][a+1][b+1][oc] fp16. m97 staging + XOR swizzle (rule #21).
// ---------------------------------------------------------------------------
template <int PLANE>
__device__ __forceinline__ void passA_body(int bid, const bf16* __restrict__ xpad,
                                           const bf16* __restrict__ wt,
                                           _Float16* __restrict__ yy, int nimg,
                                           bf16* ldsW, bf16* ldsX) {
  constexpr int M = (PLANE == 0) ? 4225 : (PLANE == 3) ? 4096 : 4160;
  constexpr int T = (M + 127) >> 7;
  constexpr int NT = (PLANE == 0) ? 4 : (PLANE == 3) ? 1 : 2;
  constexpr int AOFF = (PLANE >= 2) ? 1 : 0;
  constexpr int BOFF = (PLANE & 1) ? 1 : 0;
  constexpr int TAPI_all[4][4] = {{0, 2, 6, 8}, {1, 7, 0, 0}, {3, 5, 0, 0}, {4, 0, 0, 0}};
  constexpr int TDY_all[4][4] = {{0, 0, 1, 1}, {0, 1, 0, 0}, {0, 0, 0, 0}, {0, 0, 0, 0}};
  constexpr int TDX_all[4][4] = {{0, 1, 0, 1}, {0, 0, 0, 0}, {0, 1, 0, 0}, {0, 0, 0, 0}};

  const int t = threadIdx.x;
  const int oct = bid & 1;
  const int tmp = bid >> 1;
  const int tile = tmp % T;
  const int nl = tmp / T;
  const int m0 = tile * 128;
  const int oc0 = oct * 128;
  const bf16* xn = xpad + (size_t)nl * (66 * 66 * 256);
  _Float16* yn = yy + (size_t)(PLANE * nimg + nl) * (66 * 66 * 256);

  const int w = t >> 6, lane = t & 63;
  const int wr = w >> 1, wc = w & 1;
  const int lr = lane & 15, lg = lane >> 4;

  auto dec = [](int m, int& a, int& b) {
    if (PLANE == 0) { a = m / 65; b = m - a * 65; }
    else if (PLANE == 2) { b = m >> 6; a = m & 63; }
    else { a = m >> 6; b = m & 63; }
  };

  int xOffB[4], wOffB[4];
#pragma unroll
  for (int r = 0; r < 4; ++r) {
    const int idx = r * 256 + t;
    const int row = idx >> 3;
    const int swz = ((idx & 7) * 16) ^ ((row & 7) << 4);
    int m = m0 + row;
    if (m >= M) m = 0;  // clamped: reads valid data, store predicated off
    int a, b;
    dec(m, a, b);
    xOffB[r] = (((a + AOFF) * 66 + (b + BOFF)) * 256) * 2 + swz;
    wOffB[r] = ((oc0 + row) * 256) * 2 + swz;
  }

  f32x4 acc[4][4];
#pragma unroll
  for (int i = 0; i < 4; ++i)
#pragma unroll
    for (int j = 0; j < 4; ++j) acc[i][j] = (f32x4){0.f, 0.f, 0.f, 0.f};

  for (int ks = 0; ks < NT * 4; ++ks) {
    const int ti = ks >> 2, icb = ks & 3;
    const int xtoff = ((TDY_all[PLANE][ti] * 66 + TDX_all[PLANE][ti]) * 256 + icb * 64) * 2;
    const int wtoff = (TAPI_all[PLANE][ti] * 65536 + icb * 64) * 2;
#pragma unroll
    for (int r = 0; r < 4; ++r) {
      bf16* lw = ldsW + (size_t)(r * 256 + (t & 192)) * 8;
      bf16* lx = ldsX + (size_t)(r * 256 + (t & 192)) * 8;
      __builtin_amdgcn_global_load_lds(AS1((const char*)wt + wOffB[r] + wtoff), AS3(lw), 16, 0, 0);
      __builtin_amdgcn_global_load_lds(AS1((const char*)xn + xOffB[r] + xtoff), AS3(lx), 16, 0, 0);
    }
    __syncthreads();

#pragma unroll
    for (int kk = 0; kk < 2; ++kk) {
      bf16x8 af[4], bfr[4];
#pragma unroll
      for (int i = 0; i < 4; ++i) {
        const int row = wr * 64 + i * 16 + lr;
        const int off = row * 128 + ((kk * 64 + lg * 16) ^ ((row & 7) << 4));
        af[i] = *(const bf16x8*)((const char*)ldsW + off);
      }
#pragma unroll
      for (int j = 0; j < 4; ++j) {
        const int row = wc * 64 + j * 16 + lr;
        const int off = row * 128 + ((kk * 64 + lg * 16) ^ ((row & 7) << 4));
        bfr[j] = *(const bf16x8*)((const char*)ldsX + off);
      }
#pragma unroll
      for (int i = 0; i < 4; ++i)
#pragma unroll
        for (int j = 0; j < 4; ++j)
          acc[i][j] = __builtin_amdgcn_mfma_f32_16x16x32_bf16(af[i], bfr[j], acc[i][j], 0, 0, 0);
    }
    __syncthreads();
  }

#pragma unroll
  for (int i = 0; i < 4; ++i) {
    const int ocb = oc0 + wr * 64 + i * 16 + lg * 4;
#pragma unroll
    for (int j = 0; j < 4; ++j) {
      const int m = m0 + wc * 64 + j * 16 + lr;
      if (m < M) {
        int a, b;
        dec(m, a, b);
        h4 v;
        v[0] = (_Float16)acc[i][j][0];
        v[1] = (_Float16)acc[i][j][1];
        v[2] = (_Float16)acc[i][j][2];
        v[3] = (_Float16)acc[i][j][3];
        *(h4*)(yn + ((size_t)(a + 1) * 66 + (b + 1)) * 256 + ocb) = v;
      }
    }
  }
}

__global__ void passA_all(const bf16* __restrict__ xpad, const bf16* __restrict__ wt,
                          _Float16* __restrict__ yy, int nimg) {
  __shared__ __attribute__((aligned(16))) bf16 ldsW[128 * 64];
  __shared__ __attribute__((aligned(16))) bf16 ldsX[128 * 64];
  int bid = blockIdx.x;
  const int L0 = nimg * 68, L1 = nimg * 66, L2 = nimg * 66;
  if (bid < L0) { passA_body<0>(bid, xpad, wt, yy, nimg, ldsW, ldsX); return; }
  bid -= L0;
  if (bid < L1) { passA_body<1>(bid, xpad, wt, yy, nimg, ldsW, ldsX); return; }
  bid -= L1;
  if (bid < L2) { passA_body<2>(bid, xpad, wt, yy, nimg, ldsW, ldsX); return; }
  passA_body<3>(bid - L2, xpad, wt, yy, nimg, ldsW, ldsX);
}

// ---------------------------------------------------------------------------
// Pass B: depthwise separable 4x4 FIR on the phase planes + bias, NCHW fp32.
//  R_py0[b] = .25*yo[o-1]+.75*ye[o]+.75*yo[o]+.25*ye[o+1]
//  R_py1[b] = .25*ye[o]+.75*ye[o+1]+.75*yo[o]+.25*yo[o+1]
//  out[2p]  = .75*Rce[p]+.25*Rce[p+1]+.25*Rco[p-1]+.75*Rco[p]
//  out[2p+1]= .25*Rce[p]+.75*Rce[p+1]+.75*Rco[p]+.25*Rco[p+1]
// lane = p (coalesced float2 stores); y reads strided, L1/L2-cached.
// ---------------------------------------------------------------------------
__global__ void passB_k(const _Float16* __restrict__ yy, const float* __restrict__ bias,
                        float* __restrict__ out, int nimg, int n0) {
  const int nwg = nimg << 6;
  const int orig = blockIdx.x;
  const int qq = nwg >> 3;
  const int logical = (orig & 7) * qq + (orig >> 3);  // o-contiguous per XCD
  const int nl = logical >> 6, o = logical & 63;
  const int t = threadIdx.x;
  const int p = t & 63, g = t >> 6;
  const size_t PL = (size_t)66 * 66 * 256;
  const _Float16* Pee = yy + (size_t)(0 * nimg + nl) * PL;
  const _Float16* Peo = yy + (size_t)(1 * nimg + nl) * PL;
  const _Float16* Poe = yy + (size_t)(2 * nimg + nl) * PL;
  const _Float16* Poo = yy + (size_t)(3 * nimg + nl) * PL;
  float* ob = out + (size_t)(n0 + nl) * 256 * 128 * 128;

  for (int it = 0; it < 8; ++it) {
    const int cc = g * 64 + it * 8;
    h8 vee[2][2], voe[3][2], veo[2][3], voo[3][3];
#pragma unroll
    for (int r = 0; r < 2; ++r)
#pragma unroll
      for (int cb = 0; cb < 2; ++cb)
        vee[r][cb] = *(const h8*)(Pee + ((size_t)(o + r + 1) * 66 + (p + cb + 1)) * 256 + cc);
#pragma unroll
    for (int r = 0; r < 3; ++r)
#pragma unroll
      for (int cb = 0; cb < 2; ++cb)
        voe[r][cb] = *(const h8*)(Poe + ((size_t)(o + r) * 66 + (p + cb + 1)) * 256 + cc);
#pragma unroll
    for (int r = 0; r < 2; ++r)
#pragma unroll
      for (int cf = 0; cf < 3; ++cf)
        veo[r][cf] = *(const h8*)(Peo + ((size_t)(o + r + 1) * 66 + (p + cf)) * 256 + cc);
#pragma unroll
    for (int r = 0; r < 3; ++r)
#pragma unroll
      for (int cf = 0; cf < 3; ++cf)
        voo[r][cf] = *(const h8*)(Poo + ((size_t)(o + r) * 66 + (p + cf)) * 256 + cc);

#pragma unroll
    for (int e = 0; e < 8; ++e) {
      const float bv = bias[cc + e];
      float rce[2][2], rco[2][3];
#pragma unroll
      for (int cb = 0; cb < 2; ++cb) {
        const float e0 = (float)vee[0][cb][e], e1 = (float)vee[1][cb][e];
        const float q0 = (float)voe[0][cb][e], q1 = (float)voe[1][cb][e], q2 = (float)voe[2][cb][e];
        rce[0][cb] = 0.75f * e0 + 0.25f * e1 + 0.25f * q0 + 0.75f * q1;
        rce[1][cb] = 0.25f * e0 + 0.75f * e1 + 0.75f * q1 + 0.25f * q2;
      }
#pragma unroll
      for (int cf = 0; cf < 3; ++cf) {
        const float e0 = (float)veo[0][cf][e], e1 = (float)veo[1][cf][e];
        const float q0 = (float)voo[0][cf][e], q1 = (float)voo[1][cf][e], q2 = (float)voo[2][cf][e];
        rco[0][cf] = 0.75f * e0 + 0.25f * e1 + 0.25f * q0 + 0.75f * q1;
        rco[1][cf] = 0.25f * e0 + 0.75f * e1 + 0.75f * q1 + 0.25f * q2;
      }
#pragma unroll
      for (int py = 0; py < 2; ++py) {
        const float v0 = 0.75f * rce[py][0] + 0.25f * rce[py][1] + 0.25f * rco[py][0] +
                         0.75f * rco[py][1] + bv;
        const float v1 = 0.25f * rce[py][0] + 0.75f * rce[py][1] + 0.75f * rco[py][1] +
                         0.25f * rco[py][2] + bv;
        float2 st = {v0, v1};
        *(float2*)(ob + ((size_t)(cc + e) * 128 + (2 * o + py)) * 128 + 2 * p) = st;
      }
    }
  }
}

// ---------------------------------------------------------------------------
extern "C" void kernel_launch(void* const* d_in, const int* in_sizes, int n_in,
                              void* d_out, int out_size, void* d_ws, size_t ws_size,
                              hipStream_t stream) {
  const float* x = (const float*)d_in[0];
  const float* wgt = (const float*)d_in[1];
  const float* bias = (const float*)d_in[2];
  float* out = (float*)d_out;

  const size_t PL = (size_t)66 * 66 * 256;
  const size_t WT_BYTES = (size_t)9 * 256 * 256 * 2;  // 1.18 MB
  int c = 0;
  const int cands[5] = {16, 8, 4, 2, 1};
  for (int ci = 0; ci < 5; ++ci)
    if (WT_BYTES + (size_t)5 * cands[ci] * PL * 2 <= ws_size) { c = cands[ci]; break; }
  if (c == 0) return;

  bf16* wt = (bf16*)d_ws;
  bf16* xpad = (bf16*)((char*)d_ws + WT_BYTES);
  _Float16* yy = (_Float16*)((char*)d_ws + WT_BYTES + (size_t)c * PL * 2);

  prep_wt_k<<<256, 256, 0, stream>>>(wgt, wt);
  hipMemsetAsync(xpad, 0, (size_t)c * PL * 2, stream);
  zpad_k<<<4 * c, 256, 0, stream>>>(yy);

  for (int k = 0; k < 16 / c; ++k) {
    xpose_k<<<c * 256, 256, 0, stream>>>(x + (size_t)k * c * 1048576, xpad);
    passA_all<<<c * 264, 256, 0, stream>>>(xpad, wt, yy, c);
    passB_k<<<c * 64, 256, 0, stream>>>(yy, bias, out, c, k * c);
  }
}

// Round 4
// 449.093 us; speedup vs baseline: 1.6581x; 1.6581x over previous
//
#include <hip/hip_runtime.h>
#include <hip/hip_bf16.h>

using bf16 = __hip_bfloat16;
typedef __bf16 bf16x8 __attribute__((ext_vector_type(8)));
typedef float f32x4 __attribute__((ext_vector_type(4)));

#define AS1(p) ((const __attribute__((address_space(1))) void*)(p))
#define AS3(p) ((__attribute__((address_space(3))) void*)(p))

// ---------------------------------------------------------------------------
// Weights: Wt[tap = p*3+q][oc][ic] bf16
// ---------------------------------------------------------------------------
__global__ void prep_wt_k(const float* __restrict__ w, bf16* __restrict__ wt) {
  const int o = blockIdx.x, i = threadIdx.x;
  const float* wp = w + (size_t)(o * 256 + i) * 9;
#pragma unroll
  for (int p = 0; p < 9; ++p)
    wt[(size_t)p * 65536 + o * 256 + i] = __float2bfloat16(wp[p]);
}

// ---------------------------------------------------------------------------
// x NCHW fp32 -> padded NHWC bf16 [n][66][66][256] (border zero via memset)
// ---------------------------------------------------------------------------
__global__ void xpose_k(const float* __restrict__ x, bf16* __restrict__ xpad) {
  const int b = blockIdx.x;
  const int icb = b & 3, iy = (b >> 2) & 63, n = b >> 8;
  __shared__ bf16 lds[64][72];
  const int t = threadIdx.x;
  const int c = t & 63, ixg = t >> 6;
  const float* src = x + (((size_t)(n * 256 + icb * 64 + c) * 64 + iy) * 64);
#pragma unroll
  for (int rep = 0; rep < 4; ++rep) {
    const int ix0 = ixg * 16 + rep * 4;
    float4 v = *reinterpret_cast<const float4*>(src + ix0);
    lds[ix0 + 0][c] = __float2bfloat16(v.x);
    lds[ix0 + 1][c] = __float2bfloat16(v.y);
    lds[ix0 + 2][c] = __float2bfloat16(v.z);
    lds[ix0 + 3][c] = __float2bfloat16(v.w);
  }
  __syncthreads();
  const int ix = t >> 2, cseg = (t & 3) * 16;
  bf16* dst = xpad + (((size_t)(n * 66 + iy + 1) * 66 + ix + 1) * 256 + icb * 64 + cseg);
  typedef short short8 __attribute__((ext_vector_type(8)));
  *reinterpret_cast<short8*>(dst) = *reinterpret_cast<const short8*>(&lds[ix][cseg]);
  *reinterpret_cast<short8*>(dst + 8) = *reinterpret_cast<const short8*>(&lds[ix][cseg + 8]);
}

// ---------------------------------------------------------------------------
// Pass A: 4 y-phase GEMMs. y stored PLANAR fp16: y[plane][n][c][66][66],
// data at [a+1][b+1]. Pad ring of y is NEVER written and NEVER read (passB
// predicates) -- no cross-call state anywhere.
// ---------------------------------------------------------------------------
template <int PLANE>
__device__ __forceinline__ void passA_body(int bid, const bf16* __restrict__ xpad,
                                           const bf16* __restrict__ wt,
                                           _Float16* __restrict__ yy, int nimg,
                                           bf16* ldsW, bf16* ldsX) {
  constexpr int M = (PLANE == 0) ? 4225 : (PLANE == 3) ? 4096 : 4160;
  constexpr int T = (M + 127) >> 7;
  constexpr int NT = (PLANE == 0) ? 4 : (PLANE == 3) ? 1 : 2;
  constexpr int AOFF = (PLANE >= 2) ? 1 : 0;
  constexpr int BOFF = (PLANE & 1) ? 1 : 0;
  constexpr int TAPI_all[4][4] = {{0, 2, 6, 8}, {1, 7, 0, 0}, {3, 5, 0, 0}, {4, 0, 0, 0}};
  constexpr int TDY_all[4][4] = {{0, 0, 1, 1}, {0, 1, 0, 0}, {0, 0, 0, 0}, {0, 0, 0, 0}};
  constexpr int TDX_all[4][4] = {{0, 1, 0, 1}, {0, 0, 0, 0}, {0, 1, 0, 0}, {0, 0, 0, 0}};

  const int t = threadIdx.x;
  const int oct = bid & 1;
  const int tmp = bid >> 1;
  const int tile = tmp % T;
  const int nl = tmp / T;
  const int m0 = tile * 128;
  const int oc0 = oct * 128;
  const bf16* xn = xpad + (size_t)nl * (66 * 66 * 256);
  _Float16* yn = yy + ((size_t)(PLANE * nimg + nl) * 256) * 4356;

  const int w = t >> 6, lane = t & 63;
  const int wr = w >> 1, wc = w & 1;
  const int lr = lane & 15, lg = lane >> 4;

  // row-major decode for all planes: consecutive m -> consecutive b (coalesced
  // epilogue stores). Plane0: 65x65, plane1: 65x64, plane2: 64x65, plane3: 64x64.
  auto dec = [](int m, int& a, int& b) {
    if (PLANE == 0) { a = m / 65; b = m - a * 65; }
    else if (PLANE == 2) { a = m / 65; b = m - a * 65; }
    else { a = m >> 6; b = m & 63; }
  };

  int xOffB[4], wOffB[4];
#pragma unroll
  for (int r = 0; r < 4; ++r) {
    const int idx = r * 256 + t;
    const int row = idx >> 3;
    const int swz = ((idx & 7) * 16) ^ ((row & 7) << 4);
    int m = m0 + row;
    if (m >= M) m = 0;  // clamped: reads valid data, store predicated off
    int a, b;
    dec(m, a, b);
    xOffB[r] = (((a + AOFF) * 66 + (b + BOFF)) * 256) * 2 + swz;
    wOffB[r] = ((oc0 + row) * 256) * 2 + swz;
  }

  f32x4 acc[4][4];
#pragma unroll
  for (int i = 0; i < 4; ++i)
#pragma unroll
    for (int j = 0; j < 4; ++j) acc[i][j] = (f32x4){0.f, 0.f, 0.f, 0.f};

  for (int ks = 0; ks < NT * 4; ++ks) {
    const int ti = ks >> 2, icb = ks & 3;
    const int xtoff = ((TDY_all[PLANE][ti] * 66 + TDX_all[PLANE][ti]) * 256 + icb * 64) * 2;
    const int wtoff = (TAPI_all[PLANE][ti] * 65536 + icb * 64) * 2;
#pragma unroll
    for (int r = 0; r < 4; ++r) {
      bf16* lw = ldsW + (size_t)(r * 256 + (t & 192)) * 8;
      bf16* lx = ldsX + (size_t)(r * 256 + (t & 192)) * 8;
      __builtin_amdgcn_global_load_lds(AS1((const char*)wt + wOffB[r] + wtoff), AS3(lw), 16, 0, 0);
      __builtin_amdgcn_global_load_lds(AS1((const char*)xn + xOffB[r] + xtoff), AS3(lx), 16, 0, 0);
    }
    __syncthreads();

#pragma unroll
    for (int kk = 0; kk < 2; ++kk) {
      bf16x8 af[4], bfr[4];
#pragma unroll
      for (int i = 0; i < 4; ++i) {
        const int row = wr * 64 + i * 16 + lr;
        const int off = row * 128 + ((kk * 64 + lg * 16) ^ ((row & 7) << 4));
        af[i] = *(const bf16x8*)((const char*)ldsW + off);
      }
#pragma unroll
      for (int j = 0; j < 4; ++j) {
        const int row = wc * 64 + j * 16 + lr;
        const int off = row * 128 + ((kk * 64 + lg * 16) ^ ((row & 7) << 4));
        bfr[j] = *(const bf16x8*)((const char*)ldsX + off);
      }
#pragma unroll
      for (int i = 0; i < 4; ++i)
#pragma unroll
        for (int j = 0; j < 4; ++j)
          acc[i][j] = __builtin_amdgcn_mfma_f32_16x16x32_bf16(af[i], bfr[j], acc[i][j], 0, 0, 0);
    }
    __syncthreads();
  }

  // epilogue: planar scalar stores, 16-lane groups -> contiguous 32B runs
#pragma unroll
  for (int i = 0; i < 4; ++i) {
    const int ocb = oc0 + wr * 64 + i * 16 + lg * 4;
#pragma unroll
    for (int j = 0; j < 4; ++j) {
      const int m = m0 + wc * 64 + j * 16 + lr;
      if (m < M) {
        int a, b;
        dec(m, a, b);
        const size_t sp = (size_t)(a + 1) * 66 + (b + 1);
#pragma unroll
        for (int reg = 0; reg < 4; ++reg)
          yn[(size_t)(ocb + reg) * 4356 + sp] = (_Float16)acc[i][j][reg];
      }
    }
  }
}

__global__ void passA_all(const bf16* __restrict__ xpad, const bf16* __restrict__ wt,
                          _Float16* __restrict__ yy, int nimg) {
  __shared__ __attribute__((aligned(16))) bf16 ldsW[128 * 64];
  __shared__ __attribute__((aligned(16))) bf16 ldsX[128 * 64];
  int bid = blockIdx.x;
  const int L0 = nimg * 68, L1 = nimg * 66, L2 = nimg * 66;
  if (bid < L0) { passA_body<0>(bid, xpad, wt, yy, nimg, ldsW, ldsX); return; }
  bid -= L0;
  if (bid < L1) { passA_body<1>(bid, xpad, wt, yy, nimg, ldsW, ldsX); return; }
  bid -= L1;
  if (bid < L2) { passA_body<2>(bid, xpad, wt, yy, nimg, ldsW, ldsX); return; }
  passA_body<3>(bid - L2, xpad, wt, yy, nimg, ldsW, ldsX);
}

// ---------------------------------------------------------------------------
// Pass B: depthwise 4x4 FIR + bias on planar y. Block = (n, c); lane = col p.
// Boundary taps are predicated to 0 in registers (written extents per plane:
// ee rows1..65 cols1..65, eo rows1..65 cols1..64, oe rows1..64 cols1..65,
// oo rows1..64 cols1..64) -- the y pad ring is never read.
// ---------------------------------------------------------------------------
__global__ void passB_k(const _Float16* __restrict__ yy, const float* __restrict__ bias,
                        float* __restrict__ out, int nimg, int n0) {
  const int b = blockIdx.x;
  const int nl = b >> 8, c = b & 255;
  const int t = threadIdx.x;
  const int p = t & 63, wv = t >> 6;
  const size_t PS = (size_t)nimg * 256 * 4356;
  const _Float16* Pee = yy + ((size_t)nl * 256 + c) * 4356;
  const _Float16* Peo = Pee + PS;
  const _Float16* Poe = Pee + 2 * PS;
  const _Float16* Poo = Pee + 3 * PS;
  const float bv = bias[c];
  float* ob = out + ((size_t)(n0 + nl) * 256 + c) * 16384;

  for (int oi = 0; oi < 16; ++oi) {
    const int o = wv * 16 + oi;
    float vee[2][2], voe[3][2], veo[2][3], voo[3][3];
#pragma unroll
    for (int r = 0; r < 2; ++r)
#pragma unroll
      for (int cb = 0; cb < 2; ++cb)
        vee[r][cb] = (float)Pee[(size_t)(o + r + 1) * 66 + (p + cb + 1)];  // always in-extent
#pragma unroll
    for (int r = 0; r < 3; ++r) {
      const int row = o + r;
      const bool rok = (row >= 1) && (row <= 64);
#pragma unroll
      for (int cb = 0; cb < 2; ++cb)
        voe[r][cb] = rok ? (float)Poe[(size_t)row * 66 + (p + cb + 1)] : 0.f;
    }
#pragma unroll
    for (int r = 0; r < 2; ++r)
#pragma unroll
      for (int cf = 0; cf < 3; ++cf) {
        const int col = p + cf;
        const bool cok = (col >= 1) && (col <= 64);
        veo[r][cf] = cok ? (float)Peo[(size_t)(o + r + 1) * 66 + col] : 0.f;
      }
#pragma unroll
    for (int r = 0; r < 3; ++r) {
      const int row = o + r;
      const bool rok = (row >= 1) && (row <= 64);
#pragma unroll
      for (int cf = 0; cf < 3; ++cf) {
        const int col = p + cf;
        const bool ok = rok && (col >= 1) && (col <= 64);
        voo[r][cf] = ok ? (float)Poo[(size_t)row * 66 + col] : 0.f;
      }
    }

    float rce[2][2], rco[2][3];
#pragma unroll
    for (int cb = 0; cb < 2; ++cb) {
      rce[0][cb] = 0.75f * vee[0][cb] + 0.25f * vee[1][cb] + 0.25f * voe[0][cb] + 0.75f * voe[1][cb];
      rce[1][cb] = 0.25f * vee[0][cb] + 0.75f * vee[1][cb] + 0.75f * voe[1][cb] + 0.25f * voe[2][cb];
    }
#pragma unroll
    for (int cf = 0; cf < 3; ++cf) {
      rco[0][cf] = 0.75f * veo[0][cf] + 0.25f * veo[1][cf] + 0.25f * voo[0][cf] + 0.75f * voo[1][cf];
      rco[1][cf] = 0.25f * veo[0][cf] + 0.75f * veo[1][cf] + 0.75f * voo[1][cf] + 0.25f * voo[2][cf];
    }
#pragma unroll
    for (int py = 0; py < 2; ++py) {
      const float v0 = 0.75f * rce[py][0] + 0.25f * rce[py][1] + 0.25f * rco[py][0] +
                       0.75f * rco[py][1] + bv;
      const float v1 = 0.25f * rce[py][0] + 0.75f * rce[py][1] + 0.75f * rco[py][1] +
                       0.25f * rco[py][2] + bv;
      float2 st = {v0, v1};
      *(float2*)(ob + ((size_t)(2 * o + py)) * 128 + 2 * p) = st;
    }
  }
}

// ---------------------------------------------------------------------------
extern "C" void kernel_launch(void* const* d_in, const int* in_sizes, int n_in,
                              void* d_out, int out_size, void* d_ws, size_t ws_size,
                              hipStream_t stream) {
  const float* x = (const float*)d_in[0];
  const float* wgt = (const float*)d_in[1];
  const float* bias = (const float*)d_in[2];
  float* out = (float*)d_out;

  const size_t XPL = (size_t)66 * 66 * 256;       // xpad elems per n
  const size_t YPN = (size_t)4 * 256 * 4356;      // y elems per n
  const size_t WT_BYTES = (size_t)9 * 256 * 256 * 2;
  int c = 0;
  const int cands[5] = {16, 8, 4, 2, 1};
  for (int ci = 0; ci < 5; ++ci)
    if (WT_BYTES + (size_t)cands[ci] * (XPL + YPN) * 2 <= ws_size) { c = cands[ci]; break; }
  if (c == 0) return;

  bf16* wt = (bf16*)d_ws;
  bf16* xpad = (bf16*)((char*)d_ws + WT_BYTES);
  _Float16* yy = (_Float16*)((char*)d_ws + WT_BYTES + (size_t)c * XPL * 2);

  prep_wt_k<<<256, 256, 0, stream>>>(wgt, wt);
  hipMemsetAsync(xpad, 0, (size_t)c * XPL * 2, stream);

  for (int k = 0; k < 16 / c; ++k) {
    xpose_k<<<c * 256, 256, 0, stream>>>(x + (size_t)k * c * 1048576, xpad);
    passA_all<<<c * 264, 256, 0, stream>>>(xpad, wt, yy, c);
    passB_k<<<c * 256, 256, 0, stream>>>(yy, bias, out, c, k * c);
  }
}

// Round 6
// 310.935 us; speedup vs baseline: 2.3948x; 1.4443x over previous
//
#include <hip/hip_runtime.h>
#include <hip/hip_bf16.h>

using bf16 = __hip_bfloat16;
typedef __bf16 bf16x8 __attribute__((ext_vector_type(8)));
typedef float f32x4 __attribute__((ext_vector_type(4)));

#define AS1(p) ((const __attribute__((address_space(1))) void*)(p))
#define AS3(p) ((__attribute__((address_space(3))) void*)(p))

#define YSTRIDE 4368  // 66*66 padded to 273*16B: exact float4 staging chunks

// ---------------------------------------------------------------------------
// Weights: Wt[tap = p*3+q][oc][ic] bf16
// ---------------------------------------------------------------------------
__global__ void prep_wt_k(const float* __restrict__ w, bf16* __restrict__ wt) {
  const int o = blockIdx.x, i = threadIdx.x;
  const float* wp = w + (size_t)(o * 256 + i) * 9;
#pragma unroll
  for (int p = 0; p < 9; ++p)
    wt[(size_t)p * 65536 + o * 256 + i] = __float2bfloat16(wp[p]);
}

// ---------------------------------------------------------------------------
// x NCHW fp32 -> padded NHWC bf16 [n][66][66][256] (border zero via memset)
// ---------------------------------------------------------------------------
__global__ void xpose_k(const float* __restrict__ x, bf16* __restrict__ xpad) {
  const int b = blockIdx.x;
  const int icb = b & 3, iy = (b >> 2) & 63, n = b >> 8;
  __shared__ bf16 lds[64][72];
  const int t = threadIdx.x;
  const int c = t & 63, ixg = t >> 6;
  const float* src = x + (((size_t)(n * 256 + icb * 64 + c) * 64 + iy) * 64);
#pragma unroll
  for (int rep = 0; rep < 4; ++rep) {
    const int ix0 = ixg * 16 + rep * 4;
    float4 v = *reinterpret_cast<const float4*>(src + ix0);
    lds[ix0 + 0][c] = __float2bfloat16(v.x);
    lds[ix0 + 1][c] = __float2bfloat16(v.y);
    lds[ix0 + 2][c] = __float2bfloat16(v.z);
    lds[ix0 + 3][c] = __float2bfloat16(v.w);
  }
  __syncthreads();
  const int ix = t >> 2, cseg = (t & 3) * 16;
  bf16* dst = xpad + (((size_t)(n * 66 + iy + 1) * 66 + ix + 1) * 256 + icb * 64 + cseg);
  typedef short short8 __attribute__((ext_vector_type(8)));
  *reinterpret_cast<short8*>(dst) = *reinterpret_cast<const short8*>(&lds[ix][cseg]);
  *reinterpret_cast<short8*>(dst + 8) = *reinterpret_cast<const short8*>(&lds[ix][cseg + 8]);
}

// ---------------------------------------------------------------------------
// Pass A: 4 y-phase GEMMs. y stored PLANAR fp16: y[plane][n][c][YSTRIDE],
// data at row/col [a+1][b+1] of a 66x66 grid. Written extents:
//   ee rows1..65 cols1..65 | eo rows1..65 cols1..64
//   oe rows1..64 cols1..65 | oo rows1..64 cols1..64
// Unwritten ring cells that passB's stencil touches are zeroed IN LDS by
// passB (per-plane masks) -- no cross-call state anywhere.
// ---------------------------------------------------------------------------
template <int PLANE>
__device__ __forceinline__ void passA_body(int bid, const bf16* __restrict__ xpad,
                                           const bf16* __restrict__ wt,
                                           _Float16* __restrict__ yy, int nimg,
                                           bf16* ldsW, bf16* ldsX) {
  constexpr int M = (PLANE == 0) ? 4225 : (PLANE == 3) ? 4096 : 4160;
  constexpr int T = (M + 127) >> 7;
  constexpr int NT = (PLANE == 0) ? 4 : (PLANE == 3) ? 1 : 2;
  constexpr int AOFF = (PLANE >= 2) ? 1 : 0;
  constexpr int BOFF = (PLANE & 1) ? 1 : 0;
  constexpr int TAPI_all[4][4] = {{0, 2, 6, 8}, {1, 7, 0, 0}, {3, 5, 0, 0}, {4, 0, 0, 0}};
  constexpr int TDY_all[4][4] = {{0, 0, 1, 1}, {0, 1, 0, 0}, {0, 0, 0, 0}, {0, 0, 0, 0}};
  constexpr int TDX_all[4][4] = {{0, 1, 0, 1}, {0, 0, 0, 0}, {0, 1, 0, 0}, {0, 0, 0, 0}};

  const int t = threadIdx.x;
  const int oct = bid & 1;
  const int tmp = bid >> 1;
  const int tile = tmp % T;
  const int nl = tmp / T;
  const int m0 = tile * 128;
  const int oc0 = oct * 128;
  const bf16* xn = xpad + (size_t)nl * (66 * 66 * 256);
  _Float16* yn = yy + ((size_t)(PLANE * nimg + nl) * 256) * YSTRIDE;

  const int w = t >> 6, lane = t & 63;
  const int wr = w >> 1, wc = w & 1;
  const int lr = lane & 15, lg = lane >> 4;

  auto dec = [](int m, int& a, int& b) {
    if (PLANE == 0 || PLANE == 2) { a = m / 65; b = m - a * 65; }
    else { a = m >> 6; b = m & 63; }
  };

  int xOffB[4], wOffB[4];
#pragma unroll
  for (int r = 0; r < 4; ++r) {
    const int idx = r * 256 + t;
    const int row = idx >> 3;
    const int swz = ((idx & 7) * 16) ^ ((row & 7) << 4);
    int m = m0 + row;
    if (m >= M) m = 0;  // clamped: reads valid data, store predicated off
    int a, b;
    dec(m, a, b);
    xOffB[r] = (((a + AOFF) * 66 + (b + BOFF)) * 256) * 2 + swz;
    wOffB[r] = ((oc0 + row) * 256) * 2 + swz;
  }

  f32x4 acc[4][4];
#pragma unroll
  for (int i = 0; i < 4; ++i)
#pragma unroll
    for (int j = 0; j < 4; ++j) acc[i][j] = (f32x4){0.f, 0.f, 0.f, 0.f};

  for (int ks = 0; ks < NT * 4; ++ks) {
    const int ti = ks >> 2, icb = ks & 3;
    const int xtoff = ((TDY_all[PLANE][ti] * 66 + TDX_all[PLANE][ti]) * 256 + icb * 64) * 2;
    const int wtoff = (TAPI_all[PLANE][ti] * 65536 + icb * 64) * 2;
#pragma unroll
    for (int r = 0; r < 4; ++r) {
      bf16* lw = ldsW + (size_t)(r * 256 + (t & 192)) * 8;
      bf16* lx = ldsX + (size_t)(r * 256 + (t & 192)) * 8;
      __builtin_amdgcn_global_load_lds(AS1((const char*)wt + wOffB[r] + wtoff), AS3(lw), 16, 0, 0);
      __builtin_amdgcn_global_load_lds(AS1((const char*)xn + xOffB[r] + xtoff), AS3(lx), 16, 0, 0);
    }
    __syncthreads();

#pragma unroll
    for (int kk = 0; kk < 2; ++kk) {
      bf16x8 af[4], bfr[4];
#pragma unroll
      for (int i = 0; i < 4; ++i) {
        const int row = wr * 64 + i * 16 + lr;
        const int off = row * 128 + ((kk * 64 + lg * 16) ^ ((row & 7) << 4));
        af[i] = *(const bf16x8*)((const char*)ldsW + off);
      }
#pragma unroll
      for (int j = 0; j < 4; ++j) {
        const int row = wc * 64 + j * 16 + lr;
        const int off = row * 128 + ((kk * 64 + lg * 16) ^ ((row & 7) << 4));
        bfr[j] = *(const bf16x8*)((const char*)ldsX + off);
      }
#pragma unroll
      for (int i = 0; i < 4; ++i)
#pragma unroll
        for (int j = 0; j < 4; ++j)
          acc[i][j] = __builtin_amdgcn_mfma_f32_16x16x32_bf16(af[i], bfr[j], acc[i][j], 0, 0, 0);
    }
    __syncthreads();
  }

  // epilogue: planar scalar stores, 16-lane groups -> contiguous 32B runs
#pragma unroll
  for (int i = 0; i < 4; ++i) {
    const int ocb = oc0 + wr * 64 + i * 16 + lg * 4;
#pragma unroll
    for (int j = 0; j < 4; ++j) {
      const int m = m0 + wc * 64 + j * 16 + lr;
      if (m < M) {
        int a, b;
        dec(m, a, b);
        const size_t sp = (size_t)(a + 1) * 66 + (b + 1);
#pragma unroll
        for (int reg = 0; reg < 4; ++reg)
          yn[(size_t)(ocb + reg) * YSTRIDE + sp] = (_Float16)acc[i][j][reg];
      }
    }
  }
}

__global__ void passA_all(const bf16* __restrict__ xpad, const bf16* __restrict__ wt,
                          _Float16* __restrict__ yy, int nimg) {
  __shared__ __attribute__((aligned(16))) bf16 ldsW[128 * 64];
  __shared__ __attribute__((aligned(16))) bf16 ldsX[128 * 64];
  int bid = blockIdx.x;
  const int L0 = nimg * 68, L1 = nimg * 66, L2 = nimg * 66;
  if (bid < L0) { passA_body<0>(bid, xpad, wt, yy, nimg, ldsW, ldsX); return; }
  bid -= L0;
  if (bid < L1) { passA_body<1>(bid, xpad, wt, yy, nimg, ldsW, ldsX); return; }
  bid -= L1;
  if (bid < L2) { passA_body<2>(bid, xpad, wt, yy, nimg, ldsW, ldsX); return; }
  passA_body<3>(bid - L2, xpad, wt, yy, nimg, ldsW, ldsX);
}

// ---------------------------------------------------------------------------
// Pass B: LDS-staged depthwise 4x4 FIR + bias. Block = (n, c).
// Stage all 4 planes (34.9 KB) via float4, zero ONLY the ring cells each
// plane's stencil reads but passA didn't write (per-plane masks matching the
// round-4 predication): ee none; eo cols 0&65; oe rows 0&65; oo full ring.
// Then rolling-register separable FIR: 10 ds_read_u16 per row-pair.
// ---------------------------------------------------------------------------
__global__ void passB_k(const _Float16* __restrict__ yy, const float* __restrict__ bias,
                        float* __restrict__ out, int nimg, int n0) {
  __shared__ _Float16 ldsY[4][YSTRIDE];
  const int b = blockIdx.x;
  const int nl = b >> 8, c = b & 255;
  const int t = threadIdx.x;
  const size_t PS = (size_t)nimg * 256 * YSTRIDE;  // elems per plane-set
  const _Float16* base = yy + ((size_t)nl * 256 + c) * YSTRIDE;

  // ---- stage: 4 planes x 546 float4 chunks ----
  for (int idx = t; idx < 4 * 546; idx += 256) {
    const int pl = idx / 546, off = idx - pl * 546;
    *(float4*)(&ldsY[pl][off * 8]) =
        *(const float4*)((const char*)(base + (size_t)pl * PS) + (size_t)off * 16);
  }
  __syncthreads();
  // ---- per-plane ring zeroing (524 cells total) ----
  // idx 0..131:   eo (plane1) cols 0 & 65, rows 0..65
  // idx 132..263: oe (plane2) rows 0 & 65, cols 0..65
  // idx 264..523: oo (plane3) full ring
  for (int idx = t; idx < 524; idx += 256) {
    if (idx < 132) {
      const int r = idx >> 1, col = (idx & 1) * 65;
      ldsY[1][r * 66 + col] = (_Float16)0.f;
    } else if (idx < 264) {
      const int e = idx - 132;
      const int row = (e >= 66) ? 65 : 0, col = (e >= 66) ? e - 66 : e;
      ldsY[2][row * 66 + col] = (_Float16)0.f;
    } else {
      const int e = idx - 264;
      int pos;
      if (e < 66) pos = e;                         // row 0
      else if (e < 132) pos = 65 * 66 + (e - 66);  // row 65
      else if (e < 196) pos = (e - 131) * 66;      // col 0, rows 1..64
      else pos = (e - 195) * 66 + 65;              // col 65, rows 1..64
      ldsY[3][pos] = (_Float16)0.f;
    }
  }
  __syncthreads();

  const int p = t & 63, wv = t >> 6;
  const float bv = bias[c];
  float* ob = out + ((size_t)(n0 + nl) * 256 + c) * 16384;
  const int o0 = wv * 16;

  // rolling registers: ee rows o+1,o+2 (cols p+1,p+2); oe rows o..o+2;
  // eo rows o+1,o+2 (cols p..p+2); oo rows o..o+2.
  float eeA[2], eeB[2], oeA[2], oeB[2], oeC[2];
  float eoA[3], eoB[3], ooA[3], ooB[3], ooC[3];

#define LD2(dst, pl, row)                                  \
  { const int rb = (row) * 66 + p + 1;                     \
    dst[0] = (float)ldsY[pl][rb];                          \
    dst[1] = (float)ldsY[pl][rb + 1]; }
#define LD3(dst, pl, row)                                  \
  { const int rb = (row) * 66 + p;                         \
    dst[0] = (float)ldsY[pl][rb];                          \
    dst[1] = (float)ldsY[pl][rb + 1];                      \
    dst[2] = (float)ldsY[pl][rb + 2]; }

  LD2(eeA, 0, o0 + 1); LD2(eeB, 0, o0 + 2);
  LD2(oeA, 2, o0);     LD2(oeB, 2, o0 + 1); LD2(oeC, 2, o0 + 2);
  LD3(eoA, 1, o0 + 1); LD3(eoB, 1, o0 + 2);
  LD3(ooA, 3, o0);     LD3(ooB, 3, o0 + 1); LD3(ooC, 3, o0 + 2);

#pragma unroll
  for (int oi = 0; oi < 16; ++oi) {
    const int o = o0 + oi;
    float rce[2][2], rco[2][3];
#pragma unroll
    for (int cb = 0; cb < 2; ++cb) {
      rce[0][cb] = 0.75f * eeA[cb] + 0.25f * eeB[cb] + 0.25f * oeA[cb] + 0.75f * oeB[cb];
      rce[1][cb] = 0.25f * eeA[cb] + 0.75f * eeB[cb] + 0.75f * oeB[cb] + 0.25f * oeC[cb];
    }
#pragma unroll
    for (int cf = 0; cf < 3; ++cf) {
      rco[0][cf] = 0.75f * eoA[cf] + 0.25f * eoB[cf] + 0.25f * ooA[cf] + 0.75f * ooB[cf];
      rco[1][cf] = 0.25f * eoA[cf] + 0.75f * eoB[cf] + 0.75f * ooB[cf] + 0.25f * ooC[cf];
    }
#pragma unroll
    for (int py = 0; py < 2; ++py) {
      const float v0 = 0.75f * rce[py][0] + 0.25f * rce[py][1] + 0.25f * rco[py][0] +
                       0.75f * rco[py][1] + bv;
      const float v1 = 0.25f * rce[py][0] + 0.75f * rce[py][1] + 0.75f * rco[py][1] +
                       0.25f * rco[py][2] + bv;
      float2 st = {v0, v1};
      *(float2*)(ob + ((size_t)(2 * o + py)) * 128 + 2 * p) = st;
    }
    if (oi < 15) {  // shift down one row, load row o+3
#pragma unroll
      for (int cb = 0; cb < 2; ++cb) {
        eeA[cb] = eeB[cb]; oeA[cb] = oeB[cb]; oeB[cb] = oeC[cb];
      }
#pragma unroll
      for (int cf = 0; cf < 3; ++cf) {
        eoA[cf] = eoB[cf]; ooA[cf] = ooB[cf]; ooB[cf] = ooC[cf];
      }
      LD2(eeB, 0, o + 3);
      LD2(oeC, 2, o + 3);
      LD3(eoB, 1, o + 3);
      LD3(ooC, 3, o + 3);
    }
  }
#undef LD2
#undef LD3
}

// ---------------------------------------------------------------------------
extern "C" void kernel_launch(void* const* d_in, const int* in_sizes, int n_in,
                              void* d_out, int out_size, void* d_ws, size_t ws_size,
                              hipStream_t stream) {
  const float* x = (const float*)d_in[0];
  const float* wgt = (const float*)d_in[1];
  const float* bias = (const float*)d_in[2];
  float* out = (float*)d_out;

  const size_t XPL = (size_t)66 * 66 * 256;        // xpad elems per n
  const size_t YPN = (size_t)4 * 256 * YSTRIDE;    // y elems per n
  const size_t WT_BYTES = (size_t)9 * 256 * 256 * 2;
  int c = 0;
  const int cands[5] = {16, 8, 4, 2, 1};
  for (int ci = 0; ci < 5; ++ci)
    if (WT_BYTES + (size_t)cands[ci] * (XPL + YPN) * 2 <= ws_size) { c = cands[ci]; break; }
  if (c == 0) return;

  bf16* wt = (bf16*)d_ws;
  bf16* xpad = (bf16*)((char*)d_ws + WT_BYTES);
  _Float16* yy = (_Float16*)((char*)d_ws + WT_BYTES + (size_t)c * XPL * 2);

  prep_wt_k<<<256, 256, 0, stream>>>(wgt, wt);
  hipMemsetAsync(xpad, 0, (size_t)c * XPL * 2, stream);

  for (int k = 0; k < 16 / c; ++k) {
    xpose_k<<<c * 256, 256, 0, stream>>>(x + (size_t)k * c * 1048576, xpad);
    passA_all<<<c * 264, 256, 0, stream>>>(xpad, wt, yy, c);
    passB_k<<<c * 256, 256, 0, stream>>>(yy, bias, out, c, k * c);
  }
}

// Round 7
// 289.736 us; speedup vs baseline: 2.5700x; 1.0732x over previous
//
#include <hip/hip_runtime.h>
#include <hip/hip_bf16.h>

using bf16 = __hip_bfloat16;
typedef __bf16 bf16x8 __attribute__((ext_vector_type(8)));
typedef float f32x4 __attribute__((ext_vector_type(4)));

#define AS1(p) ((const __attribute__((address_space(1))) void*)(p))
#define AS3(p) ((__attribute__((address_space(3))) void*)(p))

#define YSTRIDE 4368  // 66*66 padded to 273*16B: exact float4 staging chunks

// ---------------------------------------------------------------------------
// Weights: Wt[tap = p*3+q][oc][ic] bf16
// ---------------------------------------------------------------------------
__global__ void prep_wt_k(const float* __restrict__ w, bf16* __restrict__ wt) {
  const int o = blockIdx.x, i = threadIdx.x;
  const float* wp = w + (size_t)(o * 256 + i) * 9;
#pragma unroll
  for (int p = 0; p < 9; ++p)
    wt[(size_t)p * 65536 + o * 256 + i] = __float2bfloat16(wp[p]);
}

// ---------------------------------------------------------------------------
// x NCHW fp32 -> padded NHWC bf16 [n][66][66][256] (border zero via memset)
// ---------------------------------------------------------------------------
__global__ void xpose_k(const float* __restrict__ x, bf16* __restrict__ xpad) {
  const int b = blockIdx.x;
  const int icb = b & 3, iy = (b >> 2) & 63, n = b >> 8;
  __shared__ bf16 lds[64][72];
  const int t = threadIdx.x;
  const int c = t & 63, ixg = t >> 6;
  const float* src = x + (((size_t)(n * 256 + icb * 64 + c) * 64 + iy) * 64);
#pragma unroll
  for (int rep = 0; rep < 4; ++rep) {
    const int ix0 = ixg * 16 + rep * 4;
    float4 v = *reinterpret_cast<const float4*>(src + ix0);
    lds[ix0 + 0][c] = __float2bfloat16(v.x);
    lds[ix0 + 1][c] = __float2bfloat16(v.y);
    lds[ix0 + 2][c] = __float2bfloat16(v.z);
    lds[ix0 + 3][c] = __float2bfloat16(v.w);
  }
  __syncthreads();
  const int ix = t >> 2, cseg = (t & 3) * 16;
  bf16* dst = xpad + (((size_t)(n * 66 + iy + 1) * 66 + ix + 1) * 256 + icb * 64 + cseg);
  typedef short short8 __attribute__((ext_vector_type(8)));
  *reinterpret_cast<short8*>(dst) = *reinterpret_cast<const short8*>(&lds[ix][cseg]);
  *reinterpret_cast<short8*>(dst + 8) = *reinterpret_cast<const short8*>(&lds[ix][cseg + 8]);
}

// ---------------------------------------------------------------------------
// Bijective XCD swizzle (m204): HW dispatch index -> logical id so each XCD
// (bid%8) owns a CONTIGUOUS logical chunk => same-image x stays L2-resident.
// ---------------------------------------------------------------------------
__device__ __forceinline__ int xcdswz(int b, int n) {
  const int q = n >> 3, r = n & 7;
  const int xcd = b & 7, idx = b >> 3;
  return (xcd < r ? xcd * (q + 1) : r * (q + 1) + (xcd - r) * q) + idx;
}

// ---------------------------------------------------------------------------
// Pass A: 4 y-phase GEMMs, m-tile 256 x oc-tile 128, 512 threads (8 waves,
// 2 oc-halves x 4 m-quarters; per-wave shapes identical to the proven
// 128x128 kernel). y stored PLANAR fp16: y[plane][n][c][YSTRIDE], data at
// [a+1][b+1] of a 66x66 grid. Written extents:
//   ee rows1..65 cols1..65 | eo rows1..65 cols1..64
//   oe rows1..64 cols1..65 | oo rows1..64 cols1..64
// Ring cells passB's stencil touches but passA doesn't write are zeroed in
// LDS by passB -- no cross-call state anywhere.
// ---------------------------------------------------------------------------
template <int PLANE>
__device__ __forceinline__ void passA_body(int bid, const bf16* __restrict__ xpad,
                                           const bf16* __restrict__ wt,
                                           _Float16* __restrict__ yy, int nimg,
                                           bf16* ldsW, bf16* ldsX) {
  constexpr int M = (PLANE == 0) ? 4225 : (PLANE == 3) ? 4096 : 4160;
  constexpr int T = (M + 255) >> 8;
  constexpr int NT = (PLANE == 0) ? 4 : (PLANE == 3) ? 1 : 2;
  constexpr int AOFF = (PLANE >= 2) ? 1 : 0;
  constexpr int BOFF = (PLANE & 1) ? 1 : 0;
  constexpr int TAPI_all[4][4] = {{0, 2, 6, 8}, {1, 7, 0, 0}, {3, 5, 0, 0}, {4, 0, 0, 0}};
  constexpr int TDY_all[4][4] = {{0, 0, 1, 1}, {0, 1, 0, 0}, {0, 0, 0, 0}, {0, 0, 0, 0}};
  constexpr int TDX_all[4][4] = {{0, 1, 0, 1}, {0, 0, 0, 0}, {0, 1, 0, 0}, {0, 0, 0, 0}};

  const int t = threadIdx.x;
  const int oct = bid & 1;
  const int tmp = bid >> 1;
  const int tile = tmp % T;
  const int nl = tmp / T;
  const int m0 = tile * 256;
  const int oc0 = oct * 128;
  const bf16* xn = xpad + (size_t)nl * (66 * 66 * 256);
  _Float16* yn = yy + ((size_t)(PLANE * nimg + nl) * 256) * YSTRIDE;

  const int w = t >> 6, lane = t & 63;
  const int wr = w >> 2, wc = w & 3;  // wr: oc 64-half, wc: m 64-quarter
  const int lr = lane & 15, lg = lane >> 4;

  auto dec = [](int m, int& a, int& b) {
    if (PLANE == 0 || PLANE == 2) { a = m / 65; b = m - a * 65; }
    else { a = m >> 6; b = m & 63; }
  };

  // staging offsets: W 1024 chunks (2/thread), X 2048 chunks (4/thread)
  int wOffB[2], xOffB[4];
#pragma unroll
  for (int r = 0; r < 2; ++r) {
    const int idx = r * 512 + t;  // 0..1023
    const int row = idx >> 3;     // 0..127 (oc row)
    const int swz = ((idx & 7) * 16) ^ ((row & 7) << 4);
    wOffB[r] = ((oc0 + row) * 256) * 2 + swz;
  }
#pragma unroll
  for (int r = 0; r < 4; ++r) {
    const int idx = r * 512 + t;  // 0..2047
    const int row = idx >> 3;     // 0..255 (m row)
    const int swz = ((idx & 7) * 16) ^ ((row & 7) << 4);
    int m = m0 + row;
    if (m >= M) m = 0;  // clamped: reads valid data, store predicated off
    int a, b;
    dec(m, a, b);
    xOffB[r] = (((a + AOFF) * 66 + (b + BOFF)) * 256) * 2 + swz;
  }

  f32x4 acc[4][4];
#pragma unroll
  for (int i = 0; i < 4; ++i)
#pragma unroll
    for (int j = 0; j < 4; ++j) acc[i][j] = (f32x4){0.f, 0.f, 0.f, 0.f};

  for (int ks = 0; ks < NT * 4; ++ks) {
    const int ti = ks >> 2, icb = ks & 3;
    const int xtoff = ((TDY_all[PLANE][ti] * 66 + TDX_all[PLANE][ti]) * 256 + icb * 64) * 2;
    const int wtoff = (TAPI_all[PLANE][ti] * 65536 + icb * 64) * 2;
#pragma unroll
    for (int r = 0; r < 2; ++r) {
      bf16* lw = ldsW + (size_t)(r * 512 + (t & 448)) * 8;  // wave-uniform base
      __builtin_amdgcn_global_load_lds(AS1((const char*)wt + wOffB[r] + wtoff), AS3(lw), 16, 0, 0);
    }
#pragma unroll
    for (int r = 0; r < 4; ++r) {
      bf16* lx = ldsX + (size_t)(r * 512 + (t & 448)) * 8;
      __builtin_amdgcn_global_load_lds(AS1((const char*)xn + xOffB[r] + xtoff), AS3(lx), 16, 0, 0);
    }
    __syncthreads();

#pragma unroll
    for (int kk = 0; kk < 2; ++kk) {
      bf16x8 af[4], bfr[4];
#pragma unroll
      for (int i = 0; i < 4; ++i) {
        const int row = wr * 64 + i * 16 + lr;
        const int off = row * 128 + ((kk * 64 + lg * 16) ^ ((row & 7) << 4));
        af[i] = *(const bf16x8*)((const char*)ldsW + off);
      }
#pragma unroll
      for (int j = 0; j < 4; ++j) {
        const int row = wc * 64 + j * 16 + lr;
        const int off = row * 128 + ((kk * 64 + lg * 16) ^ ((row & 7) << 4));
        bfr[j] = *(const bf16x8*)((const char*)ldsX + off);
      }
#pragma unroll
      for (int i = 0; i < 4; ++i)
#pragma unroll
        for (int j = 0; j < 4; ++j)
          acc[i][j] = __builtin_amdgcn_mfma_f32_16x16x32_bf16(af[i], bfr[j], acc[i][j], 0, 0, 0);
    }
    __syncthreads();
  }

  // epilogue: planar scalar stores, 16-lane groups -> contiguous 32B runs
#pragma unroll
  for (int i = 0; i < 4; ++i) {
    const int ocb = oc0 + wr * 64 + i * 16 + lg * 4;
#pragma unroll
    for (int j = 0; j < 4; ++j) {
      const int m = m0 + wc * 64 + j * 16 + lr;
      if (m < M) {
        int a, b;
        dec(m, a, b);
        const size_t sp = (size_t)(a + 1) * 66 + (b + 1);
#pragma unroll
        for (int reg = 0; reg < 4; ++reg)
          yn[(size_t)(ocb + reg) * YSTRIDE + sp] = (_Float16)acc[i][j][reg];
      }
    }
  }
}

__global__ __launch_bounds__(512) void passA_all(const bf16* __restrict__ xpad,
                                                 const bf16* __restrict__ wt,
                                                 _Float16* __restrict__ yy, int nimg) {
  __shared__ __attribute__((aligned(16))) bf16 ldsW[128 * 64];
  __shared__ __attribute__((aligned(16))) bf16 ldsX[256 * 64];
  int bid = blockIdx.x;
  const int S0 = nimg * 34, S1 = nimg * 34, S2 = nimg * 34;  // p3: nimg*32
  if (bid < S0) { passA_body<0>(xcdswz(bid, S0), xpad, wt, yy, nimg, ldsW, ldsX); return; }
  bid -= S0;
  if (bid < S1) { passA_body<1>(xcdswz(bid, S1), xpad, wt, yy, nimg, ldsW, ldsX); return; }
  bid -= S1;
  if (bid < S2) { passA_body<2>(xcdswz(bid, S2), xpad, wt, yy, nimg, ldsW, ldsX); return; }
  bid -= S2;
  passA_body<3>(xcdswz(bid, nimg * 32), xpad, wt, yy, nimg, ldsW, ldsX);
}

// ---------------------------------------------------------------------------
// Pass B: LDS-staged depthwise 4x4 FIR + bias. Block = (n, c).
// Stage all 4 planes (34.9 KB) via float4, zero ONLY the ring cells each
// plane's stencil reads but passA didn't write (per-plane masks):
// ee none; eo cols 0&65; oe rows 0&65; oo full ring.
// Then rolling-register separable FIR: 10 ds_read_u16 per row-pair.
// ---------------------------------------------------------------------------
__global__ void passB_k(const _Float16* __restrict__ yy, const float* __restrict__ bias,
                        float* __restrict__ out, int nimg, int n0) {
  __shared__ _Float16 ldsY[4][YSTRIDE];
  const int b = blockIdx.x;
  const int nl = b >> 8, c = b & 255;
  const int t = threadIdx.x;
  const size_t PS = (size_t)nimg * 256 * YSTRIDE;  // elems per plane-set
  const _Float16* base = yy + ((size_t)nl * 256 + c) * YSTRIDE;

  // ---- stage: 4 planes x 546 float4 chunks ----
  for (int idx = t; idx < 4 * 546; idx += 256) {
    const int pl = idx / 546, off = idx - pl * 546;
    *(float4*)(&ldsY[pl][off * 8]) =
        *(const float4*)((const char*)(base + (size_t)pl * PS) + (size_t)off * 16);
  }
  __syncthreads();
  // ---- per-plane ring zeroing (524 cells total) ----
  for (int idx = t; idx < 524; idx += 256) {
    if (idx < 132) {
      const int r = idx >> 1, col = (idx & 1) * 65;
      ldsY[1][r * 66 + col] = (_Float16)0.f;
    } else if (idx < 264) {
      const int e = idx - 132;
      const int row = (e >= 66) ? 65 : 0, col = (e >= 66) ? e - 66 : e;
      ldsY[2][row * 66 + col] = (_Float16)0.f;
    } else {
      const int e = idx - 264;
      int pos;
      if (e < 66) pos = e;                         // row 0
      else if (e < 132) pos = 65 * 66 + (e - 66);  // row 65
      else if (e < 196) pos = (e - 131) * 66;      // col 0, rows 1..64
      else pos = (e - 195) * 66 + 65;              // col 65, rows 1..64
      ldsY[3][pos] = (_Float16)0.f;
    }
  }
  __syncthreads();

  const int p = t & 63, wv = t >> 6;
  const float bv = bias[c];
  float* ob = out + ((size_t)(n0 + nl) * 256 + c) * 16384;
  const int o0 = wv * 16;

  float eeA[2], eeB[2], oeA[2], oeB[2], oeC[2];
  float eoA[3], eoB[3], ooA[3], ooB[3], ooC[3];

#define LD2(dst, pl, row)                                  \
  { const int rb = (row) * 66 + p + 1;                     \
    dst[0] = (float)ldsY[pl][rb];                          \
    dst[1] = (float)ldsY[pl][rb + 1]; }
#define LD3(dst, pl, row)                                  \
  { const int rb = (row) * 66 + p;                         \
    dst[0] = (float)ldsY[pl][rb];                          \
    dst[1] = (float)ldsY[pl][rb + 1];                      \
    dst[2] = (float)ldsY[pl][rb + 2]; }

  LD2(eeA, 0, o0 + 1); LD2(eeB, 0, o0 + 2);
  LD2(oeA, 2, o0);     LD2(oeB, 2, o0 + 1); LD2(oeC, 2, o0 + 2);
  LD3(eoA, 1, o0 + 1); LD3(eoB, 1, o0 + 2);
  LD3(ooA, 3, o0);     LD3(ooB, 3, o0 + 1); LD3(ooC, 3, o0 + 2);

#pragma unroll
  for (int oi = 0; oi < 16; ++oi) {
    const int o = o0 + oi;
    float rce[2][2], rco[2][3];
#pragma unroll
    for (int cb = 0; cb < 2; ++cb) {
      rce[0][cb] = 0.75f * eeA[cb] + 0.25f * eeB[cb] + 0.25f * oeA[cb] + 0.75f * oeB[cb];
      rce[1][cb] = 0.25f * eeA[cb] + 0.75f * eeB[cb] + 0.75f * oeB[cb] + 0.25f * oeC[cb];
    }
#pragma unroll
    for (int cf = 0; cf < 3; ++cf) {
      rco[0][cf] = 0.75f * eoA[cf] + 0.25f * eoB[cf] + 0.25f * ooA[cf] + 0.75f * ooB[cf];
      rco[1][cf] = 0.25f * eoA[cf] + 0.75f * eoB[cf] + 0.75f * ooB[cf] + 0.25f * ooC[cf];
    }
#pragma unroll
    for (int py = 0; py < 2; ++py) {
      const float v0 = 0.75f * rce[py][0] + 0.25f * rce[py][1] + 0.25f * rco[py][0] +
                       0.75f * rco[py][1] + bv;
      const float v1 = 0.25f * rce[py][0] + 0.75f * rce[py][1] + 0.75f * rco[py][1] +
                       0.25f * rco[py][2] + bv;
      float2 st = {v0, v1};
      *(float2*)(ob + ((size_t)(2 * o + py)) * 128 + 2 * p) = st;
    }
    if (oi < 15) {
#pragma unroll
      for (int cb = 0; cb < 2; ++cb) {
        eeA[cb] = eeB[cb]; oeA[cb] = oeB[cb]; oeB[cb] = oeC[cb];
      }
#pragma unroll
      for (int cf = 0; cf < 3; ++cf) {
        eoA[cf] = eoB[cf]; ooA[cf] = ooB[cf]; ooB[cf] = ooC[cf];
      }
      LD2(eeB, 0, o + 3);
      LD2(oeC, 2, o + 3);
      LD3(eoB, 1, o + 3);
      LD3(ooC, 3, o + 3);
    }
  }
#undef LD2
#undef LD3
}

// ---------------------------------------------------------------------------
extern "C" void kernel_launch(void* const* d_in, const int* in_sizes, int n_in,
                              void* d_out, int out_size, void* d_ws, size_t ws_size,
                              hipStream_t stream) {
  const float* x = (const float*)d_in[0];
  const float* wgt = (const float*)d_in[1];
  const float* bias = (const float*)d_in[2];
  float* out = (float*)d_out;

  const size_t XPL = (size_t)66 * 66 * 256;        // xpad elems per n
  const size_t YPN = (size_t)4 * 256 * YSTRIDE;    // y elems per n
  const size_t WT_BYTES = (size_t)9 * 256 * 256 * 2;
  int c = 0;
  const int cands[5] = {16, 8, 4, 2, 1};
  for (int ci = 0; ci < 5; ++ci)
    if (WT_BYTES + (size_t)cands[ci] * (XPL + YPN) * 2 <= ws_size) { c = cands[ci]; break; }
  if (c == 0) return;

  bf16* wt = (bf16*)d_ws;
  bf16* xpad = (bf16*)((char*)d_ws + WT_BYTES);
  _Float16* yy = (_Float16*)((char*)d_ws + WT_BYTES + (size_t)c * XPL * 2);

  prep_wt_k<<<256, 256, 0, stream>>>(wgt, wt);
  hipMemsetAsync(xpad, 0, (size_t)c * XPL * 2, stream);

  for (int k = 0; k < 16 / c; ++k) {
    xpose_k<<<c * 256, 256, 0, stream>>>(x + (size_t)k * c * 1048576, xpad);
    passA_all<<<c * 134, 512, 0, stream>>>(xpad, wt, yy, c);
    passB_k<<<c * 256, 256, 0, stream>>>(yy, bias, out, c, k * c);
  }
}

// Round 8
// 287.811 us; speedup vs baseline: 2.5872x; 1.0067x over previous
//
#include <hip/hip_runtime.h>
#include <hip/hip_bf16.h>

using bf16 = __hip_bfloat16;
typedef __bf16 bf16x8 __attribute__((ext_vector_type(8)));
typedef float f32x4 __attribute__((ext_vector_type(4)));
typedef short short8 __attribute__((ext_vector_type(8)));

#define AS1(p) ((const __attribute__((address_space(1))) void*)(p))
#define AS3(p) ((__attribute__((address_space(3))) void*)(p))

#define YSTRIDE 4368  // 66*66 padded to 273*16B: exact float4 staging chunks

// ---------------------------------------------------------------------------
// Weights: Wt[tap = p*3+q][oc][ic] bf16
// ---------------------------------------------------------------------------
__global__ void prep_wt_k(const float* __restrict__ w, bf16* __restrict__ wt) {
  const int o = blockIdx.x, i = threadIdx.x;
  const float* wp = w + (size_t)(o * 256 + i) * 9;
#pragma unroll
  for (int p = 0; p < 9; ++p)
    wt[(size_t)p * 65536 + o * 256 + i] = __float2bfloat16(wp[p]);
}

// ---------------------------------------------------------------------------
// Zero ONLY the xpad border ring (rows 0/65, cols 0/65; 260 cells x 256 ch
// per image). Replaces the 35.7 MB hipMemsetAsync (fill kernel was ~158 us
// at 225 GB/s -- the largest per-replay dispatch in round 7's profile).
// grid = nimg*33 blocks, 8 cells/block, 16B stores. Runs every call.
// ---------------------------------------------------------------------------
__global__ void zring_k(bf16* __restrict__ xpad) {
  const int bid = blockIdx.x;
  const int n = bid / 33, cg = bid - n * 33;
  const int t = threadIdx.x;
  const int cell = cg * 8 + (t >> 5);
  if (cell >= 260) return;
  int row, col;
  if (cell < 66) { row = 0; col = cell; }
  else if (cell < 132) { row = 65; col = cell - 66; }
  else if (cell < 196) { row = cell - 131; col = 0; }
  else { row = cell - 195; col = 65; }
  const int ch = (t & 31) * 8;
  short8 z = {0, 0, 0, 0, 0, 0, 0, 0};
  *(short8*)(xpad + (((size_t)n * 66 + row) * 66 + col) * 256 + ch) = z;
}

// ---------------------------------------------------------------------------
// x NCHW fp32 -> padded NHWC bf16 [n][66][66][256] (interior only; ring by
// zring_k)
// ---------------------------------------------------------------------------
__global__ void xpose_k(const float* __restrict__ x, bf16* __restrict__ xpad) {
  const int b = blockIdx.x;
  const int icb = b & 3, iy = (b >> 2) & 63, n = b >> 8;
  __shared__ bf16 lds[64][72];
  const int t = threadIdx.x;
  const int c = t & 63, ixg = t >> 6;
  const float* src = x + (((size_t)(n * 256 + icb * 64 + c) * 64 + iy) * 64);
#pragma unroll
  for (int rep = 0; rep < 4; ++rep) {
    const int ix0 = ixg * 16 + rep * 4;
    float4 v = *reinterpret_cast<const float4*>(src + ix0);
    lds[ix0 + 0][c] = __float2bfloat16(v.x);
    lds[ix0 + 1][c] = __float2bfloat16(v.y);
    lds[ix0 + 2][c] = __float2bfloat16(v.z);
    lds[ix0 + 3][c] = __float2bfloat16(v.w);
  }
  __syncthreads();
  const int ix = t >> 2, cseg = (t & 3) * 16;
  bf16* dst = xpad + (((size_t)(n * 66 + iy + 1) * 66 + ix + 1) * 256 + icb * 64 + cseg);
  *reinterpret_cast<short8*>(dst) = *reinterpret_cast<const short8*>(&lds[ix][cseg]);
  *reinterpret_cast<short8*>(dst + 8) = *reinterpret_cast<const short8*>(&lds[ix][cseg + 8]);
}

// ---------------------------------------------------------------------------
// Bijective XCD swizzle (m204): HW dispatch index -> logical id so each XCD
// (bid%8) owns a CONTIGUOUS logical chunk => same-image x stays L2-resident.
// ---------------------------------------------------------------------------
__device__ __forceinline__ int xcdswz(int b, int n) {
  const int q = n >> 3, r = n & 7;
  const int xcd = b & 7, idx = b >> 3;
  return (xcd < r ? xcd * (q + 1) : r * (q + 1) + (xcd - r) * q) + idx;
}

// ---------------------------------------------------------------------------
// Pass A: 4 y-phase GEMMs, m-tile 256 x oc-tile 128, 512 threads (8 waves,
// 2 oc-halves x 4 m-quarters). y stored PLANAR fp16: y[plane][n][c][YSTRIDE],
// data at [a+1][b+1] of a 66x66 grid. Written extents:
//   ee rows1..65 cols1..65 | eo rows1..65 cols1..64
//   oe rows1..64 cols1..65 | oo rows1..64 cols1..64
// Ring cells passB's stencil touches but passA doesn't write are zeroed in
// LDS by passB -- no cross-call state anywhere.
// ---------------------------------------------------------------------------
template <int PLANE>
__device__ __forceinline__ void passA_body(int bid, const bf16* __restrict__ xpad,
                                           const bf16* __restrict__ wt,
                                           _Float16* __restrict__ yy, int nimg,
                                           bf16* ldsW, bf16* ldsX) {
  constexpr int M = (PLANE == 0) ? 4225 : (PLANE == 3) ? 4096 : 4160;
  constexpr int T = (M + 255) >> 8;
  constexpr int NT = (PLANE == 0) ? 4 : (PLANE == 3) ? 1 : 2;
  constexpr int AOFF = (PLANE >= 2) ? 1 : 0;
  constexpr int BOFF = (PLANE & 1) ? 1 : 0;
  constexpr int TAPI_all[4][4] = {{0, 2, 6, 8}, {1, 7, 0, 0}, {3, 5, 0, 0}, {4, 0, 0, 0}};
  constexpr int TDY_all[4][4] = {{0, 0, 1, 1}, {0, 1, 0, 0}, {0, 0, 0, 0}, {0, 0, 0, 0}};
  constexpr int TDX_all[4][4] = {{0, 1, 0, 1}, {0, 0, 0, 0}, {0, 1, 0, 0}, {0, 0, 0, 0}};

  const int t = threadIdx.x;
  const int oct = bid & 1;
  const int tmp = bid >> 1;
  const int tile = tmp % T;
  const int nl = tmp / T;
  const int m0 = tile * 256;
  const int oc0 = oct * 128;
  const bf16* xn = xpad + (size_t)nl * (66 * 66 * 256);
  _Float16* yn = yy + ((size_t)(PLANE * nimg + nl) * 256) * YSTRIDE;

  const int w = t >> 6, lane = t & 63;
  const int wr = w >> 2, wc = w & 3;  // wr: oc 64-half, wc: m 64-quarter
  const int lr = lane & 15, lg = lane >> 4;

  auto dec = [](int m, int& a, int& b) {
    if (PLANE == 0 || PLANE == 2) { a = m / 65; b = m - a * 65; }
    else { a = m >> 6; b = m & 63; }
  };

  // staging offsets: W 1024 chunks (2/thread), X 2048 chunks (4/thread)
  int wOffB[2], xOffB[4];
#pragma unroll
  for (int r = 0; r < 2; ++r) {
    const int idx = r * 512 + t;  // 0..1023
    const int row = idx >> 3;     // 0..127 (oc row)
    const int swz = ((idx & 7) * 16) ^ ((row & 7) << 4);
    wOffB[r] = ((oc0 + row) * 256) * 2 + swz;
  }
#pragma unroll
  for (int r = 0; r < 4; ++r) {
    const int idx = r * 512 + t;  // 0..2047
    const int row = idx >> 3;     // 0..255 (m row)
    const int swz = ((idx & 7) * 16) ^ ((row & 7) << 4);
    int m = m0 + row;
    if (m >= M) m = 0;  // clamped: reads valid data, store predicated off
    int a, b;
    dec(m, a, b);
    xOffB[r] = (((a + AOFF) * 66 + (b + BOFF)) * 256) * 2 + swz;
  }

  f32x4 acc[4][4];
#pragma unroll
  for (int i = 0; i < 4; ++i)
#pragma unroll
    for (int j = 0; j < 4; ++j) acc[i][j] = (f32x4){0.f, 0.f, 0.f, 0.f};

  for (int ks = 0; ks < NT * 4; ++ks) {
    const int ti = ks >> 2, icb = ks & 3;
    const int xtoff = ((TDY_all[PLANE][ti] * 66 + TDX_all[PLANE][ti]) * 256 + icb * 64) * 2;
    const int wtoff = (TAPI_all[PLANE][ti] * 65536 + icb * 64) * 2;
#pragma unroll
    for (int r = 0; r < 2; ++r) {
      bf16* lw = ldsW + (size_t)(r * 512 + (t & 448)) * 8;  // wave-uniform base
      __builtin_amdgcn_global_load_lds(AS1((const char*)wt + wOffB[r] + wtoff), AS3(lw), 16, 0, 0);
    }
#pragma unroll
    for (int r = 0; r < 4; ++r) {
      bf16* lx = ldsX + (size_t)(r * 512 + (t & 448)) * 8;
      __builtin_amdgcn_global_load_lds(AS1((const char*)xn + xOffB[r] + xtoff), AS3(lx), 16, 0, 0);
    }
    __syncthreads();

#pragma unroll
    for (int kk = 0; kk < 2; ++kk) {
      bf16x8 af[4], bfr[4];
#pragma unroll
      for (int i = 0; i < 4; ++i) {
        const int row = wr * 64 + i * 16 + lr;
        const int off = row * 128 + ((kk * 64 + lg * 16) ^ ((row & 7) << 4));
        af[i] = *(const bf16x8*)((const char*)ldsW + off);
      }
#pragma unroll
      for (int j = 0; j < 4; ++j) {
        const int row = wc * 64 + j * 16 + lr;
        const int off = row * 128 + ((kk * 64 + lg * 16) ^ ((row & 7) << 4));
        bfr[j] = *(const bf16x8*)((const char*)ldsX + off);
      }
#pragma unroll
      for (int i = 0; i < 4; ++i)
#pragma unroll
        for (int j = 0; j < 4; ++j)
          acc[i][j] = __builtin_amdgcn_mfma_f32_16x16x32_bf16(af[i], bfr[j], acc[i][j], 0, 0, 0);
    }
    __syncthreads();
  }

  // epilogue: planar scalar stores, 16-lane groups -> contiguous 32B runs
#pragma unroll
  for (int i = 0; i < 4; ++i) {
    const int ocb = oc0 + wr * 64 + i * 16 + lg * 4;
#pragma unroll
    for (int j = 0; j < 4; ++j) {
      const int m = m0 + wc * 64 + j * 16 + lr;
      if (m < M) {
        int a, b;
        dec(m, a, b);
        const size_t sp = (size_t)(a + 1) * 66 + (b + 1);
#pragma unroll
        for (int reg = 0; reg < 4; ++reg)
          yn[(size_t)(ocb + reg) * YSTRIDE + sp] = (_Float16)acc[i][j][reg];
      }
    }
  }
}

__global__ __launch_bounds__(512) void passA_all(const bf16* __restrict__ xpad,
                                                 const bf16* __restrict__ wt,
                                                 _Float16* __restrict__ yy, int nimg) {
  __shared__ __attribute__((aligned(16))) bf16 ldsW[128 * 64];
  __shared__ __attribute__((aligned(16))) bf16 ldsX[256 * 64];
  int bid = blockIdx.x;
  const int S0 = nimg * 34, S1 = nimg * 34, S2 = nimg * 34;  // p3: nimg*32
  if (bid < S0) { passA_body<0>(xcdswz(bid, S0), xpad, wt, yy, nimg, ldsW, ldsX); return; }
  bid -= S0;
  if (bid < S1) { passA_body<1>(xcdswz(bid, S1), xpad, wt, yy, nimg, ldsW, ldsX); return; }
  bid -= S1;
  if (bid < S2) { passA_body<2>(xcdswz(bid, S2), xpad, wt, yy, nimg, ldsW, ldsX); return; }
  bid -= S2;
  passA_body<3>(xcdswz(bid, nimg * 32), xpad, wt, yy, nimg, ldsW, ldsX);
}

// ---------------------------------------------------------------------------
// Pass B: LDS-staged depthwise 4x4 FIR + bias. Block = (n, c).
// Stage all 4 planes (34.9 KB) via float4, zero ONLY the ring cells each
// plane's stencil reads but passA didn't write (per-plane masks):
// ee none; eo cols 0&65; oe rows 0&65; oo full ring.
// Then rolling-register separable FIR: 10 ds_read_u16 per row-pair.
// ---------------------------------------------------------------------------
__global__ void passB_k(const _Float16* __restrict__ yy, const float* __restrict__ bias,
                        float* __restrict__ out, int nimg, int n0) {
  __shared__ _Float16 ldsY[4][YSTRIDE];
  const int b = blockIdx.x;
  const int nl = b >> 8, c = b & 255;
  const int t = threadIdx.x;
  const size_t PS = (size_t)nimg * 256 * YSTRIDE;  // elems per plane-set
  const _Float16* base = yy + ((size_t)nl * 256 + c) * YSTRIDE;

  // ---- stage: 4 planes x 546 float4 chunks ----
  for (int idx = t; idx < 4 * 546; idx += 256) {
    const int pl = idx / 546, off = idx - pl * 546;
    *(float4*)(&ldsY[pl][off * 8]) =
        *(const float4*)((const char*)(base + (size_t)pl * PS) + (size_t)off * 16);
  }
  __syncthreads();
  // ---- per-plane ring zeroing (524 cells total) ----
  for (int idx = t; idx < 524; idx += 256) {
    if (idx < 132) {
      const int r = idx >> 1, col = (idx & 1) * 65;
      ldsY[1][r * 66 + col] = (_Float16)0.f;
    } else if (idx < 264) {
      const int e = idx - 132;
      const int row = (e >= 66) ? 65 : 0, col = (e >= 66) ? e - 66 : e;
      ldsY[2][row * 66 + col] = (_Float16)0.f;
    } else {
      const int e = idx - 264;
      int pos;
      if (e < 66) pos = e;                         // row 0
      else if (e < 132) pos = 65 * 66 + (e - 66);  // row 65
      else if (e < 196) pos = (e - 131) * 66;      // col 0, rows 1..64
      else pos = (e - 195) * 66 + 65;              // col 65, rows 1..64
      ldsY[3][pos] = (_Float16)0.f;
    }
  }
  __syncthreads();

  const int p = t & 63, wv = t >> 6;
  const float bv = bias[c];
  float* ob = out + ((size_t)(n0 + nl) * 256 + c) * 16384;
  const int o0 = wv * 16;

  float eeA[2], eeB[2], oeA[2], oeB[2], oeC[2];
  float eoA[3], eoB[3], ooA[3], ooB[3], ooC[3];

#define LD2(dst, pl, row)                                  \
  { const int rb = (row) * 66 + p + 1;                     \
    dst[0] = (float)ldsY[pl][rb];                          \
    dst[1] = (float)ldsY[pl][rb + 1]; }
#define LD3(dst, pl, row)                                  \
  { const int rb = (row) * 66 + p;                         \
    dst[0] = (float)ldsY[pl][rb];                          \
    dst[1] = (float)ldsY[pl][rb + 1];                      \
    dst[2] = (float)ldsY[pl][rb + 2]; }

  LD2(eeA, 0, o0 + 1); LD2(eeB, 0, o0 + 2);
  LD2(oeA, 2, o0);     LD2(oeB, 2, o0 + 1); LD2(oeC, 2, o0 + 2);
  LD3(eoA, 1, o0 + 1); LD3(eoB, 1, o0 + 2);
  LD3(ooA, 3, o0);     LD3(ooB, 3, o0 + 1); LD3(ooC, 3, o0 + 2);

#pragma unroll
  for (int oi = 0; oi < 16; ++oi) {
    const int o = o0 + oi;
    float rce[2][2], rco[2][3];
#pragma unroll
    for (int cb = 0; cb < 2; ++cb) {
      rce[0][cb] = 0.75f * eeA[cb] + 0.25f * eeB[cb] + 0.25f * oeA[cb] + 0.75f * oeB[cb];
      rce[1][cb] = 0.25f * eeA[cb] + 0.75f * eeB[cb] + 0.75f * oeB[cb] + 0.25f * oeC[cb];
    }
#pragma unroll
    for (int cf = 0; cf < 3; ++cf) {
      rco[0][cf] = 0.75f * eoA[cf] + 0.25f * eoB[cf] + 0.25f * ooA[cf] + 0.75f * ooB[cf];
      rco[1][cf] = 0.25f * eoA[cf] + 0.75f * eoB[cf] + 0.75f * ooB[cf] + 0.25f * ooC[cf];
    }
#pragma unroll
    for (int py = 0; py < 2; ++py) {
      const float v0 = 0.75f * rce[py][0] + 0.25f * rce[py][1] + 0.25f * rco[py][0] +
                       0.75f * rco[py][1] + bv;
      const float v1 = 0.25f * rce[py][0] + 0.75f * rce[py][1] + 0.75f * rco[py][1] +
                       0.25f * rco[py][2] + bv;
      float2 st = {v0, v1};
      *(float2*)(ob + ((size_t)(2 * o + py)) * 128 + 2 * p) = st;
    }
    if (oi < 15) {
#pragma unroll
      for (int cb = 0; cb < 2; ++cb) {
        eeA[cb] = eeB[cb]; oeA[cb] = oeB[cb]; oeB[cb] = oeC[cb];
      }
#pragma unroll
      for (int cf = 0; cf < 3; ++cf) {
        eoA[cf] = eoB[cf]; ooA[cf] = ooB[cf]; ooB[cf] = ooC[cf];
      }
      LD2(eeB, 0, o + 3);
      LD2(oeC, 2, o + 3);
      LD3(eoB, 1, o + 3);
      LD3(ooC, 3, o + 3);
    }
  }
#undef LD2
#undef LD3
}

// ---------------------------------------------------------------------------
extern "C" void kernel_launch(void* const* d_in, const int* in_sizes, int n_in,
                              void* d_out, int out_size, void* d_ws, size_t ws_size,
                              hipStream_t stream) {
  const float* x = (const float*)d_in[0];
  const float* wgt = (const float*)d_in[1];
  const float* bias = (const float*)d_in[2];
  float* out = (float*)d_out;

  const size_t XPL = (size_t)66 * 66 * 256;        // xpad elems per n
  const size_t YPN = (size_t)4 * 256 * YSTRIDE;    // y elems per n
  const size_t WT_BYTES = (size_t)9 * 256 * 256 * 2;
  int c = 0;
  const int cands[5] = {16, 8, 4, 2, 1};
  for (int ci = 0; ci < 5; ++ci)
    if (WT_BYTES + (size_t)cands[ci] * (XPL + YPN) * 2 <= ws_size) { c = cands[ci]; break; }
  if (c == 0) return;

  bf16* wt = (bf16*)d_ws;
  bf16* xpad = (bf16*)((char*)d_ws + WT_BYTES);
  _Float16* yy = (_Float16*)((char*)d_ws + WT_BYTES + (size_t)c * XPL * 2);

  prep_wt_k<<<256, 256, 0, stream>>>(wgt, wt);

  for (int k = 0; k < 16 / c; ++k) {
    zring_k<<<c * 33, 256, 0, stream>>>(xpad);
    xpose_k<<<c * 256, 256, 0, stream>>>(x + (size_t)k * c * 1048576, xpad);
    passA_all<<<c * 134, 512, 0, stream>>>(xpad, wt, yy, c);
    passB_k<<<c * 256, 256, 0, stream>>>(yy, bias, out, c, k * c);
  }
}

// Round 9
// 273.733 us; speedup vs baseline: 2.7203x; 1.0514x over previous
//
#include <hip/hip_runtime.h>
#include <hip/hip_bf16.h>

using bf16 = __hip_bfloat16;
typedef __bf16 bf16x8 __attribute__((ext_vector_type(8)));
typedef float f32x4 __attribute__((ext_vector_type(4)));
typedef short short8 __attribute__((ext_vector_type(8)));

#define AS1(p) ((const __attribute__((address_space(1))) void*)(p))
#define AS3(p) ((__attribute__((address_space(3))) void*)(p))

#define YSTRIDE 4368  // 66*66 padded to 273*16B: exact float4 staging chunks

// ---------------------------------------------------------------------------
// Weights: Wt[tap = p*3+q][oc][ic] bf16
// ---------------------------------------------------------------------------
__global__ void prep_wt_k(const float* __restrict__ w, bf16* __restrict__ wt) {
  const int o = blockIdx.x, i = threadIdx.x;
  const float* wp = w + (size_t)(o * 256 + i) * 9;
#pragma unroll
  for (int p = 0; p < 9; ++p)
    wt[(size_t)p * 65536 + o * 256 + i] = __float2bfloat16(wp[p]);
}

// ---------------------------------------------------------------------------
// Zero ONLY the xpad border ring (rows 0/65, cols 0/65) -- runs every call.
// ---------------------------------------------------------------------------
__global__ void zring_k(bf16* __restrict__ xpad) {
  const int bid = blockIdx.x;
  const int n = bid / 33, cg = bid - n * 33;
  const int t = threadIdx.x;
  const int cell = cg * 8 + (t >> 5);
  if (cell >= 260) return;
  int row, col;
  if (cell < 66) { row = 0; col = cell; }
  else if (cell < 132) { row = 65; col = cell - 66; }
  else if (cell < 196) { row = cell - 131; col = 0; }
  else { row = cell - 195; col = 65; }
  const int ch = (t & 31) * 8;
  short8 z = {0, 0, 0, 0, 0, 0, 0, 0};
  *(short8*)(xpad + (((size_t)n * 66 + row) * 66 + col) * 256 + ch) = z;
}

// ---------------------------------------------------------------------------
// x NCHW fp32 -> padded NHWC bf16 [n][66][66][256] (interior only)
// ---------------------------------------------------------------------------
__global__ void xpose_k(const float* __restrict__ x, bf16* __restrict__ xpad) {
  const int b = blockIdx.x;
  const int icb = b & 3, iy = (b >> 2) & 63, n = b >> 8;
  __shared__ bf16 lds[64][72];
  const int t = threadIdx.x;
  const int c = t & 63, ixg = t >> 6;
  const float* src = x + (((size_t)(n * 256 + icb * 64 + c) * 64 + iy) * 64);
#pragma unroll
  for (int rep = 0; rep < 4; ++rep) {
    const int ix0 = ixg * 16 + rep * 4;
    float4 v = *reinterpret_cast<const float4*>(src + ix0);
    lds[ix0 + 0][c] = __float2bfloat16(v.x);
    lds[ix0 + 1][c] = __float2bfloat16(v.y);
    lds[ix0 + 2][c] = __float2bfloat16(v.z);
    lds[ix0 + 3][c] = __float2bfloat16(v.w);
  }
  __syncthreads();
  const int ix = t >> 2, cseg = (t & 3) * 16;
  bf16* dst = xpad + (((size_t)(n * 66 + iy + 1) * 66 + ix + 1) * 256 + icb * 64 + cseg);
  *reinterpret_cast<short8*>(dst) = *reinterpret_cast<const short8*>(&lds[ix][cseg]);
  *reinterpret_cast<short8*>(dst + 8) = *reinterpret_cast<const short8*>(&lds[ix][cseg + 8]);
}

// ---------------------------------------------------------------------------
// Bijective XCD swizzle (m204)
// ---------------------------------------------------------------------------
__device__ __forceinline__ int xcdswz(int b, int n) {
  const int q = n >> 3, r = n & 7;
  const int xcd = b & 7, idx = b >> 3;
  return (xcd < r ? xcd * (q + 1) : r * (q + 1) + (xcd - r) * q) + idx;
}

// ---------------------------------------------------------------------------
// Pass A: 4 y-phase GEMMs, FULL 256oc x 256m per block (512 thr, 8 waves =
// 4 oc x 2 m; per-wave 64oc x 128m, acc[4][8]). X staged ONCE per m-tile
// (was twice with split oc) -> staged volume 933->~620 MB.
// y stored PLANAR fp16: y[plane][n][c][YSTRIDE], data at [a+1][b+1].
// Written extents: ee r1..65 c1..65 | eo r1..65 c1..64
//                  oe r1..64 c1..65 | oo r1..64 c1..64
// ---------------------------------------------------------------------------
template <int PLANE>
__device__ __forceinline__ void passA_body(int bid, const bf16* __restrict__ xpad,
                                           const bf16* __restrict__ wt,
                                           _Float16* __restrict__ yy, int nimg,
                                           bf16* ldsW, bf16* ldsX) {
  constexpr int M = (PLANE == 0) ? 4225 : (PLANE == 3) ? 4096 : 4160;
  constexpr int T = (M + 255) >> 8;
  constexpr int NT = (PLANE == 0) ? 4 : (PLANE == 3) ? 1 : 2;
  constexpr int AOFF = (PLANE >= 2) ? 1 : 0;
  constexpr int BOFF = (PLANE & 1) ? 1 : 0;
  constexpr int TAPI_all[4][4] = {{0, 2, 6, 8}, {1, 7, 0, 0}, {3, 5, 0, 0}, {4, 0, 0, 0}};
  constexpr int TDY_all[4][4] = {{0, 0, 1, 1}, {0, 1, 0, 0}, {0, 0, 0, 0}, {0, 0, 0, 0}};
  constexpr int TDX_all[4][4] = {{0, 1, 0, 1}, {0, 0, 0, 0}, {0, 1, 0, 0}, {0, 0, 0, 0}};

  const int t = threadIdx.x;
  const int tile = bid % T;
  const int nl = bid / T;
  const int m0 = tile * 256;
  const bf16* xn = xpad + (size_t)nl * (66 * 66 * 256);
  _Float16* yn = yy + ((size_t)(PLANE * nimg + nl) * 256) * YSTRIDE;

  const int w = t >> 6, lane = t & 63;
  const int wr = w >> 1, wc = w & 1;  // wr: oc quarter (0..3), wc: m half (0..1)
  const int lr = lane & 15, lg = lane >> 4;

  auto dec = [](int m, int& a, int& b) {
    if (PLANE == 0 || PLANE == 2) { a = m / 65; b = m - a * 65; }
    else { a = m >> 6; b = m & 63; }
  };

  // staging offsets: W 2048 chunks (4/thread), X 2048 chunks (4/thread)
  int wOffB[4], xOffB[4];
#pragma unroll
  for (int r = 0; r < 4; ++r) {
    const int idx = r * 512 + t;  // 0..2047
    const int row = idx >> 3;     // 0..255
    const int swz = ((idx & 7) * 16) ^ ((row & 7) << 4);
    wOffB[r] = (row * 256) * 2 + swz;  // oc row
    int m = m0 + row;
    if (m >= M) m = 0;  // clamped: reads valid data, store predicated off
    int a, b;
    dec(m, a, b);
    xOffB[r] = (((a + AOFF) * 66 + (b + BOFF)) * 256) * 2 + swz;
  }

  f32x4 acc[4][8];
#pragma unroll
  for (int i = 0; i < 4; ++i)
#pragma unroll
    for (int j = 0; j < 8; ++j) acc[i][j] = (f32x4){0.f, 0.f, 0.f, 0.f};

  for (int ks = 0; ks < NT * 4; ++ks) {
    const int ti = ks >> 2, icb = ks & 3;
    const int xtoff = ((TDY_all[PLANE][ti] * 66 + TDX_all[PLANE][ti]) * 256 + icb * 64) * 2;
    const int wtoff = (TAPI_all[PLANE][ti] * 65536 + icb * 64) * 2;
#pragma unroll
    for (int r = 0; r < 4; ++r) {
      bf16* lw = ldsW + (size_t)(r * 512 + (t & 448)) * 8;  // wave-uniform base
      __builtin_amdgcn_global_load_lds(AS1((const char*)wt + wOffB[r] + wtoff), AS3(lw), 16, 0, 0);
    }
#pragma unroll
    for (int r = 0; r < 4; ++r) {
      bf16* lx = ldsX + (size_t)(r * 512 + (t & 448)) * 8;
      __builtin_amdgcn_global_load_lds(AS1((const char*)xn + xOffB[r] + xtoff), AS3(lx), 16, 0, 0);
    }
    __syncthreads();

#pragma unroll
    for (int kk = 0; kk < 2; ++kk) {
      bf16x8 af[4], bfr[8];
#pragma unroll
      for (int i = 0; i < 4; ++i) {
        const int row = wr * 64 + i * 16 + lr;
        const int off = row * 128 + ((kk * 64 + lg * 16) ^ ((row & 7) << 4));
        af[i] = *(const bf16x8*)((const char*)ldsW + off);
      }
#pragma unroll
      for (int j = 0; j < 8; ++j) {
        const int row = wc * 128 + j * 16 + lr;
        const int off = row * 128 + ((kk * 64 + lg * 16) ^ ((row & 7) << 4));
        bfr[j] = *(const bf16x8*)((const char*)ldsX + off);
      }
#pragma unroll
      for (int i = 0; i < 4; ++i)
#pragma unroll
        for (int j = 0; j < 8; ++j)
          acc[i][j] = __builtin_amdgcn_mfma_f32_16x16x32_bf16(af[i], bfr[j], acc[i][j], 0, 0, 0);
    }
    __syncthreads();
  }

  // epilogue: planar scalar stores, 16-lane groups -> contiguous 32B runs
#pragma unroll
  for (int i = 0; i < 4; ++i) {
    const int ocb = wr * 64 + i * 16 + lg * 4;
#pragma unroll
    for (int j = 0; j < 8; ++j) {
      const int m = m0 + wc * 128 + j * 16 + lr;
      if (m < M) {
        int a, b;
        dec(m, a, b);
        const size_t sp = (size_t)(a + 1) * 66 + (b + 1);
#pragma unroll
        for (int reg = 0; reg < 4; ++reg)
          yn[(size_t)(ocb + reg) * YSTRIDE + sp] = (_Float16)acc[i][j][reg];
      }
    }
  }
}

__global__ __launch_bounds__(512) void passA_all(const bf16* __restrict__ xpad,
                                                 const bf16* __restrict__ wt,
                                                 _Float16* __restrict__ yy, int nimg) {
  __shared__ __attribute__((aligned(16))) bf16 ldsW[256 * 64];
  __shared__ __attribute__((aligned(16))) bf16 ldsX[256 * 64];
  int bid = blockIdx.x;
  const int S0 = nimg * 17, S1 = nimg * 17, S2 = nimg * 17;  // p3: nimg*16
  if (bid < S0) { passA_body<0>(xcdswz(bid, S0), xpad, wt, yy, nimg, ldsW, ldsX); return; }
  bid -= S0;
  if (bid < S1) { passA_body<1>(xcdswz(bid, S1), xpad, wt, yy, nimg, ldsW, ldsX); return; }
  bid -= S1;
  if (bid < S2) { passA_body<2>(xcdswz(bid, S2), xpad, wt, yy, nimg, ldsW, ldsX); return; }
  bid -= S2;
  passA_body<3>(xcdswz(bid, nimg * 16), xpad, wt, yy, nimg, ldsW, ldsX);
}

// ---------------------------------------------------------------------------
// Pass B: LDS-staged depthwise 4x4 FIR + bias. Block = (n, c, half): rows
// [R0..R0+33] of each plane staged (18 KB -> 8 blocks/CU, 32 waves/CU).
// Ring cells read-but-unwritten are zeroed per-plane/per-half in LDS:
// ee none; eo cols 0&65 (all rows); oe/oo boundary row (global 0 or 65);
// oo also cols 0&65. Rolling-register FIR, 8 row-pairs per wave.
// ---------------------------------------------------------------------------
#define BSTRIDE 2248  // 34*66=2244 padded to 16B multiple

__global__ void passB_k(const _Float16* __restrict__ yy, const float* __restrict__ bias,
                        float* __restrict__ out, int nimg, int n0) {
  __shared__ _Float16 ldsY[4][BSTRIDE];
  const int b = blockIdx.x;
  const int h = b & 1, c = (b >> 1) & 255, nl = b >> 9;
  const int R0 = h * 32;
  const int t = threadIdx.x;
  const size_t PS = (size_t)nimg * 256 * YSTRIDE;
  const _Float16* base = yy + ((size_t)nl * 256 + c) * YSTRIDE;

  // ---- stage: 4 planes x 281 float4 chunks (rows R0..R0+33 + 8B slack) ----
  for (int idx = t; idx < 4 * 281; idx += 256) {
    const int pl = idx / 281, off = idx - pl * 281;
    *(float4*)(&ldsY[pl][off * 8]) =
        *(const float4*)((const char*)(base + (size_t)pl * PS) + R0 * 132 + (size_t)off * 16);
  }
  __syncthreads();
  // ---- ring zeroing (268 cells) ----
  const int brel = h ? 33 : 0;  // rel row of global row 0 (h=0) or 65 (h=1)
  for (int idx = t; idx < 268; idx += 256) {
    if (idx < 68) {                       // eo: cols 0 & 65, all rel rows
      const int r = idx >> 1, col = (idx & 1) * 65;
      ldsY[1][r * 66 + col] = (_Float16)0.f;
    } else if (idx < 134) {               // oe: boundary row
      ldsY[2][brel * 66 + (idx - 68)] = (_Float16)0.f;
    } else if (idx < 200) {               // oo: boundary row
      ldsY[3][brel * 66 + (idx - 134)] = (_Float16)0.f;
    } else {                              // oo: cols 0 & 65, all rel rows
      const int k = idx - 200;
      const int r = k >> 1, col = (k & 1) * 65;
      ldsY[3][r * 66 + col] = (_Float16)0.f;
    }
  }
  __syncthreads();

  const int p = t & 63, wv = t >> 6;
  const float bv = bias[c];
  float* ob = out + ((size_t)(n0 + nl) * 256 + c) * 16384;
  const int r0 = wv * 8;  // rel row base for this wave (8 row-pairs)

  float eeA[2], eeB[2], oeA[2], oeB[2], oeC[2];
  float eoA[3], eoB[3], ooA[3], ooB[3], ooC[3];

#define LD2(dst, pl, row)                                  \
  { const int rb = (row) * 66 + p + 1;                     \
    dst[0] = (float)ldsY[pl][rb];                          \
    dst[1] = (float)ldsY[pl][rb + 1]; }
#define LD3(dst, pl, row)                                  \
  { const int rb = (row) * 66 + p;                         \
    dst[0] = (float)ldsY[pl][rb];                          \
    dst[1] = (float)ldsY[pl][rb + 1];                      \
    dst[2] = (float)ldsY[pl][rb + 2]; }

  LD2(eeA, 0, r0 + 1); LD2(eeB, 0, r0 + 2);
  LD2(oeA, 2, r0);     LD2(oeB, 2, r0 + 1); LD2(oeC, 2, r0 + 2);
  LD3(eoA, 1, r0 + 1); LD3(eoB, 1, r0 + 2);
  LD3(ooA, 3, r0);     LD3(ooB, 3, r0 + 1); LD3(ooC, 3, r0 + 2);

#pragma unroll
  for (int oi = 0; oi < 8; ++oi) {
    const int o = R0 + r0 + oi;
    float rce[2][2], rco[2][3];
#pragma unroll
    for (int cb = 0; cb < 2; ++cb) {
      rce[0][cb] = 0.75f * eeA[cb] + 0.25f * eeB[cb] + 0.25f * oeA[cb] + 0.75f * oeB[cb];
      rce[1][cb] = 0.25f * eeA[cb] + 0.75f * eeB[cb] + 0.75f * oeB[cb] + 0.25f * oeC[cb];
    }
#pragma unroll
    for (int cf = 0; cf < 3; ++cf) {
      rco[0][cf] = 0.75f * eoA[cf] + 0.25f * eoB[cf] + 0.25f * ooA[cf] + 0.75f * ooB[cf];
      rco[1][cf] = 0.25f * eoA[cf] + 0.75f * eoB[cf] + 0.75f * ooB[cf] + 0.25f * ooC[cf];
    }
#pragma unroll
    for (int py = 0; py < 2; ++py) {
      const float v0 = 0.75f * rce[py][0] + 0.25f * rce[py][1] + 0.25f * rco[py][0] +
                       0.75f * rco[py][1] + bv;
      const float v1 = 0.25f * rce[py][0] + 0.75f * rce[py][1] + 0.75f * rco[py][1] +
                       0.25f * rco[py][2] + bv;
      float2 st = {v0, v1};
      *(float2*)(ob + ((size_t)(2 * o + py)) * 128 + 2 * p) = st;
    }
    if (oi < 7) {  // shift down one row, load rel row r0+oi+3 (max 33)
#pragma unroll
      for (int cb = 0; cb < 2; ++cb) {
        eeA[cb] = eeB[cb]; oeA[cb] = oeB[cb]; oeB[cb] = oeC[cb];
      }
#pragma unroll
      for (int cf = 0; cf < 3; ++cf) {
        eoA[cf] = eoB[cf]; ooA[cf] = ooB[cf]; ooB[cf] = ooC[cf];
      }
      LD2(eeB, 0, r0 + oi + 3);
      LD2(oeC, 2, r0 + oi + 3);
      LD3(eoB, 1, r0 + oi + 3);
      LD3(ooC, 3, r0 + oi + 3);
    }
  }
#undef LD2
#undef LD3
}

// ---------------------------------------------------------------------------
extern "C" void kernel_launch(void* const* d_in, const int* in_sizes, int n_in,
                              void* d_out, int out_size, void* d_ws, size_t ws_size,
                              hipStream_t stream) {
  const float* x = (const float*)d_in[0];
  const float* wgt = (const float*)d_in[1];
  const float* bias = (const float*)d_in[2];
  float* out = (float*)d_out;

  const size_t XPL = (size_t)66 * 66 * 256;        // xpad elems per n
  const size_t YPN = (size_t)4 * 256 * YSTRIDE;    // y elems per n
  const size_t WT_BYTES = (size_t)9 * 256 * 256 * 2;
  int c = 0;
  const int cands[5] = {16, 8, 4, 2, 1};
  for (int ci = 0; ci < 5; ++ci)
    if (WT_BYTES + (size_t)cands[ci] * (XPL + YPN) * 2 <= ws_size) { c = cands[ci]; break; }
  if (c == 0) return;

  bf16* wt = (bf16*)d_ws;
  bf16* xpad = (bf16*)((char*)d_ws + WT_BYTES);
  _Float16* yy = (_Float16*)((char*)d_ws + WT_BYTES + (size_t)c * XPL * 2);

  prep_wt_k<<<256, 256, 0, stream>>>(wgt, wt);

  for (int k = 0; k < 16 / c; ++k) {
    zring_k<<<c * 33, 256, 0, stream>>>(xpad);
    xpose_k<<<c * 256, 256, 0, stream>>>(x + (size_t)k * c * 1048576, xpad);
    passA_all<<<c * 67, 512, 0, stream>>>(xpad, wt, yy, c);
    passB_k<<<c * 512, 256, 0, stream>>>(yy, bias, out, c, k * c);
  }
}